// Round 1
// baseline (1534.660 us; speedup 1.0000x reference)
//
#include <hip/hip_runtime.h>
#include <hip/hip_bf16.h>

typedef __hip_bfloat16 bf16;
typedef short s16x8 __attribute__((ext_vector_type(8)));
typedef float f32x4 __attribute__((ext_vector_type(4)));

#define DIM   1536
#define HEADS 24
#define HD    64
#define TOTAL 3072
#define ENCR  384
#define INNER 6144
#define SIX   9216

// ---- dtype-agnostic loads: flag==1 -> inputs are float32, flag==0 -> bf16
__device__ __forceinline__ float ldf(const void* p, size_t i, int f) {
    return f ? ((const float*)p)[i]
             : __bfloat162float(((const bf16*)p)[i]);
}
__device__ __forceinline__ short f2s(float v) {
    bf16 b = __float2bfloat16(v);
    short s; __builtin_memcpy(&s, &b, 2); return s;
}
__device__ __forceinline__ s16x8 ldb8(const void* B, size_t i, int f) {
    s16x8 r;
    if (f) {
        const float4* p = (const float4*)((const float*)B + i);
        float4 x = p[0], y = p[1];
        r[0]=f2s(x.x); r[1]=f2s(x.y); r[2]=f2s(x.z); r[3]=f2s(x.w);
        r[4]=f2s(y.x); r[5]=f2s(y.y); r[6]=f2s(y.z); r[7]=f2s(y.w);
    } else {
        r = *(const s16x8*)((const short*)B + i);
    }
    return r;
}
// async global->LDS, 16B per lane; lds base must be wave-uniform
__device__ __forceinline__ void gld16(const void* g, void* l) {
    __builtin_amdgcn_global_load_lds(
        (const __attribute__((address_space(1))) unsigned int*)g,
        (__attribute__((address_space(3))) unsigned int*)l, 16, 0, 0);
}

// ---------------- probe: detect input dtype (bf16 vs f32-as-shorts)
__global__ __launch_bounds__(256) void probe_kernel(const unsigned short* __restrict__ w,
                                                    int* __restrict__ flag) {
    __shared__ int cnt;
    if (threadIdx.x == 0) cnt = 0;
    __syncthreads();
    int local = 0;
    for (int i = threadIdx.x; i < 65536; i += 256) {
        unsigned short u = w[i];
        if (((u >> 7) & 0xFF) == 0xFF) local++;
    }
    atomicAdd(&cnt, local);
    __syncthreads();
    if (threadIdx.x == 0) flag[0] = (cnt > 0) ? 1 : 0;
}

// ---------------------------------------------------------------- silu(temb)
__global__ __launch_bounds__(256) void silu_kernel(const void* __restrict__ temb,
                                                   float* __restrict__ sact,
                                                   const int* __restrict__ flag) {
    int f = flag[0];
    int i = blockIdx.x * 256 + threadIdx.x;
    float x = ldf(temb, i, f);
    sact[i] = x / (1.f + __expf(-x));
}

// -------------------------------------------- e6 = silu(temb) @ W + b (3x9216)
__global__ __launch_bounds__(256) void ada_kernel(const float* __restrict__ sact,
                                                  const void* __restrict__ W,
                                                  const void* __restrict__ bias,
                                                  float* __restrict__ out,
                                                  const int* __restrict__ flag) {
    int f = flag[0];
    __shared__ float red[3][4][64];
    int c   = threadIdx.x & 63;
    int col = blockIdx.x * 64 + c;
    int kq  = threadIdx.x >> 6;
    float a0 = 0.f, a1 = 0.f, a2 = 0.f;
    for (int k = kq * 384; k < kq * 384 + 384; ++k) {
        float wv = ldf(W, (size_t)k * SIX + col, f);
        a0 += sact[k] * wv;
        a1 += sact[1536 + k] * wv;
        a2 += sact[3072 + k] * wv;
    }
    red[0][kq][c] = a0; red[1][kq][c] = a1; red[2][kq][c] = a2;
    __syncthreads();
    if (kq < 3) {
        float s = red[kq][0][c] + red[kq][1][c] + red[kq][2][c] + red[kq][3][c]
                + ldf(bias, col, f);
        out[(size_t)kq * SIX + col] = s;
    }
}

// ------------------------- LayerNorm + AdaLN modulate
__global__ __launch_bounds__(256) void ln_mod_kernel(const void* __restrict__ x,
                                                     const float* __restrict__ ada,
                                                     bf16* __restrict__ out,
                                                     int shift_sel, int scale_sel,
                                                     int is_enc, int x_dual,
                                                     const int* __restrict__ flag) {
    int f = x_dual ? flag[0] : 0;
    __shared__ float r1[256], r2[256];
    int t = blockIdx.x, tid = threadIdx.x;
    int stage = is_enc ? (t >> 7) : (t < 512 ? 0 : (t < 1536 ? 1 : 2));
    float v[6]; float s = 0.f, s2 = 0.f;
#pragma unroll
    for (int i = 0; i < 6; ++i) {
        float a = ldf(x, (size_t)t * DIM + tid + i * 256, f);
        v[i] = a; s += a; s2 += a * a;
    }
    r1[tid] = s; r2[tid] = s2;
    __syncthreads();
    for (int st = 128; st; st >>= 1) {
        if (tid < st) { r1[tid] += r1[tid + st]; r2[tid] += r2[tid + st]; }
        __syncthreads();
    }
    float mean = r1[0] * (1.f / 1536.f);
    float var  = fmaxf(r2[0] * (1.f / 1536.f) - mean * mean, 0.f);
    float inv  = rsqrtf(var + 1e-6f);
    const float* ab = ada + (size_t)stage * SIX;
#pragma unroll
    for (int i = 0; i < 6; ++i) {
        int c = tid + i * 256;
        float sc = ab[scale_sel * DIM + c];
        float sh = ab[shift_sel * DIM + c];
        out[(size_t)t * DIM + c] = __float2bfloat16((v[i] - mean) * inv * (1.f + sc) + sh);
    }
}

// ---------- fused: res = base + gate*delta (store), then LN(res)+modulate -> out
__global__ __launch_bounds__(256) void resid_ln_kernel(const void* __restrict__ base,
                                                       const bf16* __restrict__ delta,
                                                       const float* __restrict__ ada,
                                                       int gate_sel, int shift_sel,
                                                       int scale_sel, int is_enc,
                                                       bf16* __restrict__ res,
                                                       bf16* __restrict__ out,
                                                       int base_dual,
                                                       const int* __restrict__ flag) {
    int f = base_dual ? flag[0] : 0;
    __shared__ float r1[256], r2[256];
    int t = blockIdx.x, tid = threadIdx.x;
    int stage = is_enc ? (t >> 7) : (t < 512 ? 0 : (t < 1536 ? 1 : 2));
    const float* ab = ada + (size_t)stage * SIX;
    float v[6]; float s = 0.f, s2 = 0.f;
#pragma unroll
    for (int i = 0; i < 6; ++i) {
        int c = tid + i * 256;
        size_t gi = (size_t)t * DIM + c;
        float g = ab[gate_sel * DIM + c];
        float a = ldf(base, gi, f) + g * __bfloat162float(delta[gi]);
        res[gi] = __float2bfloat16(a);
        v[i] = a; s += a; s2 += a * a;
    }
    r1[tid] = s; r2[tid] = s2;
    __syncthreads();
    for (int st = 128; st; st >>= 1) {
        if (tid < st) { r1[tid] += r1[tid + st]; r2[tid] += r2[tid + st]; }
        __syncthreads();
    }
    float mean = r1[0] * (1.f / 1536.f);
    float var  = fmaxf(r2[0] * (1.f / 1536.f) - mean * mean, 0.f);
    float inv  = rsqrtf(var + 1e-6f);
#pragma unroll
    for (int i = 0; i < 6; ++i) {
        int c = tid + i * 256;
        float sc = ab[scale_sel * DIM + c];
        float sh = ab[shift_sel * DIM + c];
        out[(size_t)t * DIM + c] = __float2bfloat16((v[i] - mean) * inv * (1.f + sc) + sh);
    }
}

// -------------------------- weight transpose: W[K][N] -> WT[N][K] (bf16 out)
// grid (N/64, K/64), block 256
__global__ __launch_bounds__(256) void wt_kernel(const void* __restrict__ W,
                                                 bf16* __restrict__ WT,
                                                 int K, int N,
                                                 const int* __restrict__ flag) {
    int f = flag[0];
    __shared__ short T[64][72];
    int n0 = blockIdx.x * 64, k0 = blockIdx.y * 64;
    int tid = threadIdx.x;
    int r = tid >> 2, c0 = (tid & 3) * 16;
#pragma unroll
    for (int i = 0; i < 16; ++i)
        T[r][c0 + i] = f2s(ldf(W, (size_t)(k0 + r) * N + n0 + c0 + i, f));
    __syncthreads();
    int n = tid >> 2, kc = (tid & 3) * 16;
    s16x8 o0, o1;
#pragma unroll
    for (int i = 0; i < 8; ++i) o0[i] = T[kc + i][n];
#pragma unroll
    for (int i = 0; i < 8; ++i) o1[i] = T[kc + 8 + i][n];
    short* orow = (short*)WT + (size_t)(n0 + n) * K + k0 + kc;
    *(s16x8*)orow = o0;
    *(s16x8*)(orow + 8) = o1;
}

// ------------------------- transposed-B MFMA GEMM (m97-style, async staging)
// C[M, Nout(xn)] = act(A[M,K] @ Bt[N,K]^T + bias).  128x128 tile, BK=64
// (two 32-wide LDS halves per barrier pair -> half the barrier drains of BK=32).
// Up to 3 stacked output buffers (fused QKV): sel = n0 / Nout.
// XOR chunk swizzle on the global side of global_load_lds kills LDS read
// conflicts (2 rows per (parity,chunk) slot -> 2-way, free per m136).
__global__ __launch_bounds__(256) void gemm_t_kernel(const short* __restrict__ A,
                                                     const short* __restrict__ Bt,
                                                     const void* __restrict__ B0,
                                                     const void* __restrict__ B1,
                                                     const void* __restrict__ B2,
                                                     bf16* __restrict__ O0,
                                                     bf16* __restrict__ O1,
                                                     bf16* __restrict__ O2,
                                                     int Nout, int K, int act,
                                                     const int* __restrict__ flag) {
    int f = flag[0];
    __shared__ __align__(16) short As[2 * 128 * 32];
    __shared__ __align__(16) short Bs[2 * 128 * 32];
    int tid = threadIdx.x;
    int lane = tid & 63, wid = tid >> 6;
    int wy = wid >> 1, wx = wid & 1;
    int lane15 = lane & 15, quad = lane >> 4;
    int m0 = blockIdx.y * 128, n0 = blockIdx.x * 128;
    int lr = lane >> 2, lc = lane & 3;

    f32x4 acc[4][4] = {};

    for (int k0 = 0; k0 < K; k0 += 64) {
        __syncthreads();
#pragma unroll
        for (int c = 0; c < 2; ++c) {
            int rb = wid * 32 + c * 16;
            int r = rb + lr;
            int gc = (lc - (r >> 1)) & 3;
            const short* arow = A  + (size_t)(m0 + r) * K + k0 + gc * 8;
            const short* brow = Bt + (size_t)(n0 + r) * K + k0 + gc * 8;
            gld16(arow,      &As[rb * 32]);
            gld16(arow + 32, &As[4096 + rb * 32]);
            gld16(brow,      &Bs[rb * 32]);
            gld16(brow + 32, &Bs[4096 + rb * 32]);
        }
        __syncthreads();   // compiler drains vmcnt before s_barrier
#pragma unroll
        for (int h = 0; h < 2; ++h) {
            const short* Ash = &As[h * 4096];
            const short* Bsh = &Bs[h * 4096];
            s16x8 af[4], bfr[4];
#pragma unroll
            for (int i = 0; i < 4; ++i) {
                int ra = wy * 64 + i * 16 + lane15;
                af[i] = *(const s16x8*)&Ash[ra * 32 + ((quad + (ra >> 1)) & 3) * 8];
                int rb2 = wx * 64 + i * 16 + lane15;
                bfr[i] = *(const s16x8*)&Bsh[rb2 * 32 + ((quad + (rb2 >> 1)) & 3) * 8];
            }
#pragma unroll
            for (int im = 0; im < 4; ++im)
#pragma unroll
                for (int in = 0; in < 4; ++in)
                    acc[im][in] = __builtin_amdgcn_mfma_f32_16x16x32_bf16(
                        af[im], bfr[in], acc[im][in], 0, 0, 0);
        }
    }

    int sel = n0 / Nout;
    int nb = n0 - sel * Nout;
    bf16* Cout = sel == 0 ? O0 : (sel == 1 ? O1 : O2);
    const void* bs = sel == 0 ? B0 : (sel == 1 ? B1 : B2);

#pragma unroll
    for (int in = 0; in < 4; ++in) {
        int gn = nb + wx * 64 + in * 16 + lane15;
        float bsv = ldf(bs, gn, f);
#pragma unroll
        for (int im = 0; im < 4; ++im) {
#pragma unroll
            for (int r = 0; r < 4; ++r) {
                int gm = m0 + wy * 64 + im * 16 + quad * 4 + r;
                float v = acc[im][in][r] + bsv;
                if (act == 1) {
                    float xx = v;
                    v = 0.5f * xx * (1.f + tanhf(0.7978845608028654f *
                                                 (xx + 0.044715f * xx * xx * xx)));
                }
                Cout[(size_t)gm * Nout + gn] = __float2bfloat16(v);
            }
        }
    }
}

// ---------------------------------------------------------------- legacy GEMM
// (fallback when ws is too small for transposed weights)
#define LDK 48
__global__ __launch_bounds__(256) void gemm_kernel(const short* __restrict__ A,
                                                   const void* __restrict__ B,
                                                   const void* __restrict__ bias,
                                                   bf16* __restrict__ C,
                                                   int M, int N, int K, int act,
                                                   const int* __restrict__ flag) {
    int f = flag[0];
    __shared__ __align__(16) short As[128 * LDK];
    __shared__ __align__(16) short Bs[128 * LDK];
    int tid = threadIdx.x;
    int lane = tid & 63, wid = tid >> 6;
    int wy = wid >> 1, wx = wid & 1;
    int m16 = lane & 15, quad = lane >> 4;
    int m0 = blockIdx.y * 128, n0 = blockIdx.x * 128;
    int ar0 = tid >> 2;
    int ac  = (tid & 3) * 8;
    int br0 = tid >> 4;
    int bc  = (tid & 15) * 8;
    f32x4 acc[4][4] = {};
    for (int k0 = 0; k0 < K; k0 += 32) {
        s16x8 a0 = *(const s16x8*)(A + (size_t)(m0 + ar0) * K + k0 + ac);
        s16x8 a1 = *(const s16x8*)(A + (size_t)(m0 + ar0 + 64) * K + k0 + ac);
        s16x8 b0 = ldb8(B, (size_t)(k0 + br0) * N + n0 + bc, f);
        s16x8 b1 = ldb8(B, (size_t)(k0 + br0 + 16) * N + n0 + bc, f);
        __syncthreads();
        *(s16x8*)(&As[ar0 * LDK + ac]) = a0;
        *(s16x8*)(&As[(ar0 + 64) * LDK + ac]) = a1;
#pragma unroll
        for (int i = 0; i < 8; ++i) {
            Bs[(bc + i) * LDK + br0] = b0[i];
            Bs[(bc + i) * LDK + br0 + 16] = b1[i];
        }
        __syncthreads();
        s16x8 af[4], bfr[4];
#pragma unroll
        for (int i = 0; i < 4; ++i) {
            af[i]  = *(const s16x8*)(&As[(wy * 64 + i * 16 + m16) * LDK + quad * 8]);
            bfr[i] = *(const s16x8*)(&Bs[(wx * 64 + i * 16 + m16) * LDK + quad * 8]);
        }
#pragma unroll
        for (int im = 0; im < 4; ++im)
#pragma unroll
            for (int in = 0; in < 4; ++in)
                acc[im][in] = __builtin_amdgcn_mfma_f32_16x16x32_bf16(
                    af[im], bfr[in], acc[im][in], 0, 0, 0);
    }
#pragma unroll
    for (int in = 0; in < 4; ++in) {
        int gn = n0 + wx * 64 + in * 16 + m16;
        float bsv = ldf(bias, gn, f);
#pragma unroll
        for (int im = 0; im < 4; ++im) {
#pragma unroll
            for (int r = 0; r < 4; ++r) {
                int gm = m0 + wy * 64 + im * 16 + quad * 4 + r;
                float v = acc[im][in][r] + bsv;
                if (act == 1) {
                    float xx = v;
                    v = 0.5f * xx * (1.f + tanhf(0.7978845608028654f *
                                                 (xx + 0.044715f * xx * xx * xx)));
                }
                C[(size_t)gm * N + gn] = __float2bfloat16(v);
            }
        }
    }
}

// --------- fused per-(token,head) RMSNorm (over 64) + rotation-matrix RoPE
// 32 lanes per (token,head); lane l holds elems 2l,2l+1 -> RoPE pair in-lane.
__global__ __launch_bounds__(256) void rmsrope_kernel(bf16* __restrict__ x,
                                                      const void* __restrict__ w,
                                                      const void* __restrict__ r0,
                                                      const void* __restrict__ r1,
                                                      const void* __restrict__ r2,
                                                      int is_enc,
                                                      const int* __restrict__ flag) {
    int f = flag[0];
    int grp = blockIdx.x * 8 + (threadIdx.x >> 5);
    int l = threadIdx.x & 31;
    int t = grp / 24;
    size_t base = (size_t)grp * 64 + 2 * l;
    unsigned int u = *(const unsigned int*)((const short*)x + base);
    union { unsigned int ui; float fl; } a, b;
    a.ui = (u & 0xFFFFu) << 16;
    b.ui = u & 0xFFFF0000u;
    float x0 = a.fl, x1 = b.fl;
    float ss = x0 * x0 + x1 * x1;
#pragma unroll
    for (int off = 1; off < 32; off <<= 1) ss += __shfl_xor(ss, off);
    float inv = rsqrtf(ss * (1.f / 64.f) + 1e-6f);
    float xw0 = x0 * inv * ldf(w, 2 * l, f);
    float xw1 = x1 * inv * ldf(w, 2 * l + 1, f);
    int stage, pos;
    if (is_enc)        { stage = t >> 7; pos = t & 127; }
    else if (t < 512)  { stage = 0; pos = 128 + t; }
    else if (t < 1536) { stage = 1; pos = 128 + t - 512; }
    else               { stage = 2; pos = 128 + t - 1536; }
    const void* rt = stage == 0 ? r0 : (stage == 1 ? r1 : r2);
    size_t ro = ((size_t)pos * 32 + l) * 4;
    float c00 = ldf(rt, ro + 0, f);
    float c01 = ldf(rt, ro + 1, f);
    float c10 = ldf(rt, ro + 2, f);
    float c11 = ldf(rt, ro + 3, f);
    unsigned int o0 = (unsigned int)(unsigned short)f2s(c00 * xw0 + c01 * xw1);
    unsigned int o1 = (unsigned int)(unsigned short)f2s(c10 * xw0 + c11 * xw1);
    *(unsigned int*)((short*)x + base) = (o1 << 16) | o0;
}

// ------------------------------------- build VJt[h][d][token] per stage (for PV)
__global__ __launch_bounds__(256) void vjt_kernel(const bf16* __restrict__ Vb,
                                                  const bf16* __restrict__ EVb,
                                                  bf16* __restrict__ VJt) {
    __shared__ short T[64][72];
    int b = blockIdx.x;
    int h = b % 24, jt = b / 24;
    int s, j0, S, hbase; size_t off;
    if (jt < 10)      { s = 0; j0 = jt * 64;        S = 640;  hbase = 0;    off = 0; }
    else if (jt < 28) { s = 1; j0 = (jt - 10) * 64; S = 1152; hbase = 512;  off = (size_t)24 * 64 * 640; }
    else              { s = 2; j0 = (jt - 28) * 64; S = 1664; hbase = 1536; off = (size_t)24 * 64 * (640 + 1152); }
    int tid = threadIdx.x;
    int tr = tid >> 2, tc = (tid & 3) * 16;
    int j = j0 + tr;
    const bf16* vr = (j < 128) ? EVb + ((size_t)(s * 128 + j) * DIM + h * HD)
                               : Vb + ((size_t)(hbase + j - 128) * DIM + h * HD);
    *(s16x8*)&T[tr][tc]     = *(const s16x8*)((const short*)vr + tc);
    *(s16x8*)&T[tr][tc + 8] = *(const s16x8*)((const short*)vr + tc + 8);
    __syncthreads();
    int d = tid >> 2, c0 = (tid & 3) * 16;
    s16x8 o0, o1;
#pragma unroll
    for (int i = 0; i < 8; ++i) o0[i] = T[c0 + i][d];
#pragma unroll
    for (int i = 0; i < 8; ++i) o1[i] = T[c0 + 8 + i][d];
    short* orow = (short*)VJt + off + (size_t)(h * HD + d) * S + j0 + c0;
    *(s16x8*)orow = o0;
    *(s16x8*)(orow + 8) = o1;
}

// -------------------------------------------------- MFMA tiled flash attention
// KVBLK=64: half the barriers / softmax shuffles / P-LDS round-trips per key
// vs the KVBLK=32 version.  Block order reversed so longest-S tiles start first.
__global__ __launch_bounds__(256) void attn_mfma_kernel(const bf16* __restrict__ Qb,
                                                        const bf16* __restrict__ Kb,
                                                        const bf16* __restrict__ EQ,
                                                        const bf16* __restrict__ EK,
                                                        const bf16* __restrict__ VJt,
                                                        const int* __restrict__ encv,
                                                        bf16* __restrict__ AH,
                                                        bf16* __restrict__ AE) {
    __shared__ __align__(16) short Ks[64 * 72];
    __shared__ __align__(16) short Vt[64 * 72];
    __shared__ __align__(16) short Ps[4][16 * 72];
    int tid = threadIdx.x, wid = tid >> 6, lane = tid & 63;
    int lane15 = lane & 15, quad = lane >> 4;
    int b = (int)gridDim.x - 1 - (int)blockIdx.x;
    int h = b % 24, qt = b / 24;
    int s, qt0, S, hbase; size_t voff;
    if (qt < 10)      { s = 0; qt0 = qt;      S = 640;  hbase = 0;    voff = 0; }
    else if (qt < 28) { s = 1; qt0 = qt - 10; S = 1152; hbase = 512;  voff = (size_t)24 * 64 * 640; }
    else              { s = 2; qt0 = qt - 28; S = 1664; hbase = 1536; voff = (size_t)24 * 64 * (640 + 1152); }
    const short* vbase = (const short*)VJt + voff + (size_t)h * HD * S;
    int ev = encv[s];
    int qbase = qt0 * 64 + wid * 16;

    int q = qbase + lane15;
    const short* qrow = (q < 128)
        ? (const short*)EQ + ((size_t)(s * 128 + q) * DIM + h * HD)
        : (const short*)Qb + ((size_t)(hbase + q - 128) * DIM + h * HD);
    s16x8 qa[2];
#pragma unroll
    for (int k0 = 0; k0 < 2; ++k0) {
        s16x8 x = *(const s16x8*)(qrow + k0 * 32 + quad * 8);
#pragma unroll
        for (int i = 0; i < 8; ++i) {
            union { unsigned int u; float fl; } t;
            t.u = ((unsigned int)(unsigned short)x[i]) << 16;
            t.fl *= 0.125f;
            x[i] = (short)(t.u >> 16);
        }
        qa[k0] = x;
    }

    f32x4 o[4] = {};
    float mrun[4] = {-1e30f, -1e30f, -1e30f, -1e30f};
    float lrun[4] = {};

    int nkb = S >> 6;
    for (int kb = 0; kb < nkb; ++kb) {
        __syncthreads();
        {
            int kr = tid >> 2, kc = (tid & 3) * 16;
            int kg = kb * 64 + kr;
            const short* krow = (kg < 128)
                ? (const short*)EK + ((size_t)(s * 128 + kg) * DIM + h * HD)
                : (const short*)Kb + ((size_t)(hbase + kg - 128) * DIM + h * HD);
            *(s16x8*)&Ks[kr * 72 + kc]     = *(const s16x8*)(krow + kc);
            *(s16x8*)&Ks[kr * 72 + kc + 8] = *(const s16x8*)(krow + kc + 8);
        }
        {
            int vd = tid >> 2, vc = (tid & 3) * 16;
            const short* vrow = vbase + (size_t)vd * S + kb * 64 + vc;
            *(s16x8*)&Vt[vd * 72 + vc]     = *(const s16x8*)(vrow);
            *(s16x8*)&Vt[vd * 72 + vc + 8] = *(const s16x8*)(vrow + 8);
        }
        __syncthreads();

        f32x4 sacc[4];
        __builtin_amdgcn_s_setprio(1);
#pragma unroll
        for (int g = 0; g < 4; ++g) {
            s16x8 kf0 = *(const s16x8*)&Ks[(g * 16 + lane15) * 72 + quad * 8];
            s16x8 kf1 = *(const s16x8*)&Ks[(g * 16 + lane15) * 72 + 32 + quad * 8];
            f32x4 c = {};
            c = __builtin_amdgcn_mfma_f32_16x16x32_bf16(qa[0], kf0, c, 0, 0, 0);
            c = __builtin_amdgcn_mfma_f32_16x16x32_bf16(qa[1], kf1, c, 0, 0, 0);
            sacc[g] = c;
        }
        __builtin_amdgcn_s_setprio(0);
        if (kb == 1) {             // keys 64..127 are the only maskable ones (ev>=64)
#pragma unroll
            for (int g = 0; g < 4; ++g) {
                int keyg = 64 + g * 16 + lane15;
                if (keyg >= ev) {
#pragma unroll
                    for (int r = 0; r < 4; ++r) sacc[g][r] = -1e30f;
                }
            }
        }
        float mt[4], al[4], ps[4];
#pragma unroll
        for (int r = 0; r < 4; ++r)
            mt[r] = fmaxf(fmaxf(sacc[0][r], sacc[1][r]), fmaxf(sacc[2][r], sacc[3][r]));
#pragma unroll
        for (int off = 1; off < 16; off <<= 1)
#pragma unroll
            for (int r = 0; r < 4; ++r) mt[r] = fmaxf(mt[r], __shfl_xor(mt[r], off));
#pragma unroll
        for (int r = 0; r < 4; ++r) {
            float mn = fmaxf(mrun[r], mt[r]);
            al[r] = __expf(mrun[r] - mn);
            mrun[r] = mn;
        }
#pragma unroll
        for (int g = 0; g < 4; ++g)
#pragma unroll
            for (int r = 0; r < 4; ++r)
                sacc[g][r] = __expf(sacc[g][r] - mrun[r]);
#pragma unroll
        for (int r = 0; r < 4; ++r)
            ps[r] = (sacc[0][r] + sacc[1][r]) + (sacc[2][r] + sacc[3][r]);
#pragma unroll
        for (int off = 1; off < 16; off <<= 1)
#pragma unroll
            for (int r = 0; r < 4; ++r) ps[r] += __shfl_xor(ps[r], off);
#pragma unroll
        for (int r = 0; r < 4; ++r) lrun[r] = lrun[r] * al[r] + ps[r];
#pragma unroll
        for (int dc = 0; dc < 4; ++dc)
#pragma unroll
            for (int r = 0; r < 4; ++r) o[dc][r] *= al[r];
#pragma unroll
        for (int g = 0; g < 4; ++g)
#pragma unroll
            for (int r = 0; r < 4; ++r)
                Ps[wid][(quad * 4 + r) * 72 + g * 16 + lane15] = f2s(sacc[g][r]);
        s16x8 pa0 = *(const s16x8*)&Ps[wid][lane15 * 72 + quad * 8];
        s16x8 pa1 = *(const s16x8*)&Ps[wid][lane15 * 72 + 32 + quad * 8];
        __builtin_amdgcn_s_setprio(1);
#pragma unroll
        for (int dc = 0; dc < 4; ++dc) {
            s16x8 vf0 = *(const s16x8*)&Vt[(dc * 16 + lane15) * 72 + quad * 8];
            s16x8 vf1 = *(const s16x8*)&Vt[(dc * 16 + lane15) * 72 + 32 + quad * 8];
            o[dc] = __builtin_amdgcn_mfma_f32_16x16x32_bf16(pa0, vf0, o[dc], 0, 0, 0);
            o[dc] = __builtin_amdgcn_mfma_f32_16x16x32_bf16(pa1, vf1, o[dc], 0, 0, 0);
        }
        __builtin_amdgcn_s_setprio(0);
    }

    float invl[4];
#pragma unroll
    for (int r = 0; r < 4; ++r) invl[r] = 1.f / fmaxf(lrun[r], 1e-37f);
#pragma unroll
    for (int r = 0; r < 4; ++r) {
        int qr = qbase + quad * 4 + r;
        bf16* orow = (qr < 128)
            ? AE + ((size_t)(s * 128 + qr) * DIM + h * HD)
            : AH + ((size_t)(hbase + qr - 128) * DIM + h * HD);
#pragma unroll
        for (int dc = 0; dc < 4; ++dc)
            orow[dc * 16 + lane15] = __float2bfloat16(o[dc][r] * invl[r]);
    }
}

// --------------------- out = base + gate[stage]*delta
__global__ __launch_bounds__(256) void resid_kernel(const void* __restrict__ base,
                                                    const bf16* __restrict__ delta,
                                                    const float* __restrict__ ada,
                                                    int gate_sel, int is_enc,
                                                    void* __restrict__ out,
                                                    size_t out_off,
                                                    int base_dual, int out_dual,
                                                    const int* __restrict__ flag) {
    int bfl = base_dual ? flag[0] : 0;
    int ofl = out_dual ? flag[0] : 0;
    int gid = blockIdx.x * 256 + threadIdx.x;
    int t = gid / DIM, c = gid - t * DIM;
    int stage = is_enc ? (t >> 7) : (t < 512 ? 0 : (t < 1536 ? 1 : 2));
    float g = ada[(size_t)stage * SIX + gate_sel * DIM + c];
    float v = ldf(base, gid, bfl) + g * __bfloat162float(delta[gid]);
    if (ofl) ((float*)out)[out_off + gid] = v;
    else     ((bf16*)out)[out_off + gid] = __float2bfloat16(v);
}

extern "C" void kernel_launch(void* const* d_in, const int* in_sizes, int n_in,
                              void* d_out, int out_size, void* d_ws, size_t ws_size,
                              hipStream_t stream) {
    (void)in_sizes; (void)n_in; (void)out_size;
    const void* hid   = d_in[0];
    const void* enc   = d_in[1];
    const void* temb  = d_in[2];
    const int*  encv  = (const int*)d_in[3];
    const void* rope0 = d_in[4];
    const void* rope1 = d_in[5];
    const void* rope2 = d_in[6];
    const void* ada_w = d_in[7];  const void* ada_b = d_in[8];
    const void* ada_cw = d_in[9]; const void* ada_cb = d_in[10];
    const void* wq = d_in[11]; const void* bq = d_in[12];
    const void* wk = d_in[13]; const void* bk = d_in[14];
    const void* wv = d_in[15]; const void* bv = d_in[16];
    const void* waq = d_in[17]; const void* baq = d_in[18];
    const void* wak = d_in[19]; const void* bak = d_in[20];
    const void* wav = d_in[21]; const void* bav = d_in[22];
    const void* nq_w = d_in[23];
    const void* nk_w = d_in[24];
    const void* naq_w = d_in[25];
    const void* nak_w = d_in[26];
    const void* wo = d_in[27]; const void* bo = d_in[28];
    const void* wao = d_in[29]; const void* bao = d_in[30];
    const void* ffw1 = d_in[31]; const void* ffb1 = d_in[32];
    const void* ffw2 = d_in[33]; const void* ffb2 = d_in[34];
    const void* fcw1 = d_in[35]; const void* fcb1 = d_in[36];
    const void* fcw2 = d_in[37]; const void* fcb2 = d_in[38];

    char* ws = (char*)d_ws;
    size_t off = 0;
    auto alloc = [&](size_t bytes) {
        char* p = ws + off;
        off = (off + bytes + 255) & ~(size_t)255;
        return p;
    };
    int*   FLAG = (int*)alloc(256);
    float* SACT = (float*)alloc(3 * 1536 * 4);
    float* E6   = (float*)alloc((size_t)3 * SIX * 4);
    float* EC   = (float*)alloc((size_t)3 * SIX * 4);
    bf16* NH  = (bf16*)alloc((size_t)TOTAL * DIM * 2);
    bf16* NE  = (bf16*)alloc((size_t)ENCR * DIM * 2);
    bf16* Qb  = (bf16*)alloc((size_t)TOTAL * DIM * 2);
    bf16* Kb  = (bf16*)alloc((size_t)TOTAL * DIM * 2);
    bf16* Vb  = (bf16*)alloc((size_t)TOTAL * DIM * 2);
    bf16* EQb = (bf16*)alloc((size_t)ENCR * DIM * 2);
    bf16* EKb = (bf16*)alloc((size_t)ENCR * DIM * 2);
    bf16* EVb = (bf16*)alloc((size_t)ENCR * DIM * 2);
    bf16* VJT = (bf16*)alloc((size_t)24 * 64 * (640 + 1152 + 1664) * 2);
    bf16* FF1  = (bf16*)alloc((size_t)TOTAL * INNER * 2);
    bf16* FFC1 = (bf16*)alloc((size_t)ENCR * INNER * 2);
    // transposed weights
    const size_t SQ = (size_t)DIM * DIM;          // 1536*1536
    const size_t RC = (size_t)DIM * INNER;        // 1536*6144
    bf16* WQKVT  = (bf16*)alloc(3 * SQ * 2);      // wqT|wkT|wvT  rows 0..4607
    bf16* WAQKVT = (bf16*)alloc(3 * SQ * 2);
    bf16* WOT    = (bf16*)alloc(SQ * 2);
    bf16* WAOT   = (bf16*)alloc(SQ * 2);
    bf16* FFW1T  = (bf16*)alloc(RC * 2);          // [6144][1536]
    bf16* FFW2T  = (bf16*)alloc(RC * 2);          // [1536][6144]
    bf16* FCW1T  = (bf16*)alloc(RC * 2);
    bf16* FCW2T  = (bf16*)alloc(RC * 2);
    bool useT = (off <= ws_size);

    // 0. dtype probe
    probe_kernel<<<1, 256, 0, stream>>>((const unsigned short*)ada_w, FLAG);

    // 0b. weight transposes
    if (useT) {
        dim3 gsq(24, 24), g16(96, 24), g61(24, 96);
        wt_kernel<<<gsq, 256, 0, stream>>>(wq,  WQKVT,           DIM, DIM, FLAG);
        wt_kernel<<<gsq, 256, 0, stream>>>(wk,  WQKVT + SQ,      DIM, DIM, FLAG);
        wt_kernel<<<gsq, 256, 0, stream>>>(wv,  WQKVT + 2 * SQ,  DIM, DIM, FLAG);
        wt_kernel<<<gsq, 256, 0, stream>>>(waq, WAQKVT,          DIM, DIM, FLAG);
        wt_kernel<<<gsq, 256, 0, stream>>>(wak, WAQKVT + SQ,     DIM, DIM, FLAG);
        wt_kernel<<<gsq, 256, 0, stream>>>(wav, WAQKVT + 2 * SQ, DIM, DIM, FLAG);
        wt_kernel<<<gsq, 256, 0, stream>>>(wo,  WOT,  DIM, DIM, FLAG);
        wt_kernel<<<gsq, 256, 0, stream>>>(wao, WAOT, DIM, DIM, FLAG);
        wt_kernel<<<g16, 256, 0, stream>>>(ffw1, FFW1T, DIM, INNER, FLAG);
        wt_kernel<<<g61, 256, 0, stream>>>(ffw2, FFW2T, INNER, DIM, FLAG);
        wt_kernel<<<g16, 256, 0, stream>>>(fcw1, FCW1T, DIM, INNER, FLAG);
        wt_kernel<<<g61, 256, 0, stream>>>(fcw2, FCW2T, INNER, DIM, FLAG);
    }

    // 1. AdaLN tables
    silu_kernel<<<18, 256, 0, stream>>>(temb, SACT, FLAG);
    ada_kernel<<<144, 256, 0, stream>>>(SACT, ada_w, ada_b, E6, FLAG);
    ada_kernel<<<144, 256, 0, stream>>>(SACT, ada_cw, ada_cb, EC, FLAG);

    // 2. LN + modulate (msa)
    ln_mod_kernel<<<TOTAL, 256, 0, stream>>>(hid, E6, NH, 0, 1, 0, 1, FLAG);
    ln_mod_kernel<<<ENCR, 256, 0, stream>>>(enc, EC, NE, 0, 1, 1, 1, FLAG);

    // 3. QKV projections
    if (useT) {
        gemm_t_kernel<<<dim3(36, 24), 256, 0, stream>>>((const short*)NH, (const short*)WQKVT,
            bq, bk, bv, Qb, Kb, Vb, DIM, DIM, 0, FLAG);
        gemm_t_kernel<<<dim3(36, 3), 256, 0, stream>>>((const short*)NE, (const short*)WAQKVT,
            baq, bak, bav, EQb, EKb, EVb, DIM, DIM, 0, FLAG);
    } else {
        dim3 gh(12, 24), ge(12, 3);
        gemm_kernel<<<gh, 256, 0, stream>>>((const short*)NH, wq, bq, Qb, TOTAL, DIM, DIM, 0, FLAG);
        gemm_kernel<<<gh, 256, 0, stream>>>((const short*)NH, wk, bk, Kb, TOTAL, DIM, DIM, 0, FLAG);
        gemm_kernel<<<gh, 256, 0, stream>>>((const short*)NH, wv, bv, Vb, TOTAL, DIM, DIM, 0, FLAG);
        gemm_kernel<<<ge, 256, 0, stream>>>((const short*)NE, waq, baq, EQb, ENCR, DIM, DIM, 0, FLAG);
        gemm_kernel<<<ge, 256, 0, stream>>>((const short*)NE, wak, bak, EKb, ENCR, DIM, DIM, 0, FLAG);
        gemm_kernel<<<ge, 256, 0, stream>>>((const short*)NE, wav, bav, EVb, ENCR, DIM, DIM, 0, FLAG);
    }

    // 4. fused per-head RMSNorm + RoPE on q/k
    rmsrope_kernel<<<(TOTAL * HEADS) / 8, 256, 0, stream>>>(Qb, nq_w, rope0, rope1, rope2, 0, FLAG);
    rmsrope_kernel<<<(TOTAL * HEADS) / 8, 256, 0, stream>>>(Kb, nk_w, rope0, rope1, rope2, 0, FLAG);
    rmsrope_kernel<<<(ENCR * HEADS) / 8, 256, 0, stream>>>(EQb, naq_w, rope0, rope1, rope2, 1, FLAG);
    rmsrope_kernel<<<(ENCR * HEADS) / 8, 256, 0, stream>>>(EKb, nak_w, rope0, rope1, rope2, 1, FLAG);

    // 4b. V joint-transpose for PV B-fragments
    vjt_kernel<<<1296, 256, 0, stream>>>(Vb, EVb, VJT);

    // 5. MFMA flash attention (writes ATT_H->NH, ATT_E->NE)
    attn_mfma_kernel<<<1296, 256, 0, stream>>>(Qb, Kb, EQb, EKb, VJT, encv, NH, NE);

    // 6. output projections (PROJ_H->Qb, PROJ_E->EQb)
    if (useT) {
        gemm_t_kernel<<<dim3(12, 24), 256, 0, stream>>>((const short*)NH, (const short*)WOT,
            bo, bo, bo, Qb, Qb, Qb, DIM, DIM, 0, FLAG);
        gemm_t_kernel<<<dim3(12, 3), 256, 0, stream>>>((const short*)NE, (const short*)WAOT,
            bao, bao, bao, EQb, EQb, EQb, DIM, DIM, 0, FLAG);
    } else {
        dim3 gh(12, 24), ge(12, 3);
        gemm_kernel<<<gh, 256, 0, stream>>>((const short*)NH, wo, bo, Qb, TOTAL, DIM, DIM, 0, FLAG);
        gemm_kernel<<<ge, 256, 0, stream>>>((const short*)NE, wao, bao, EQb, ENCR, DIM, DIM, 0, FLAG);
    }

    // 7+8. fused gated residual #1 + LN + modulate (mlp)
    //      hidden: res->Kb, ln_mod->Vb ; enc: res->EKb, ln_mod->EVb
    resid_ln_kernel<<<TOTAL, 256, 0, stream>>>(hid, Qb, E6, 2, 3, 4, 0, Kb, Vb, 1, FLAG);
    resid_ln_kernel<<<ENCR, 256, 0, stream>>>(enc, EQb, EC, 2, 3, 4, 1, EKb, EVb, 1, FLAG);

    // 9. FFN
    if (useT) {
        gemm_t_kernel<<<dim3(48, 24), 256, 0, stream>>>((const short*)Vb, (const short*)FFW1T,
            ffb1, ffb1, ffb1, FF1, FF1, FF1, INNER, DIM, 1, FLAG);
        gemm_t_kernel<<<dim3(48, 3), 256, 0, stream>>>((const short*)EVb, (const short*)FCW1T,
            fcb1, fcb1, fcb1, FFC1, FFC1, FFC1, INNER, DIM, 1, FLAG);
        gemm_t_kernel<<<dim3(12, 24), 256, 0, stream>>>((const short*)FF1, (const short*)FFW2T,
            ffb2, ffb2, ffb2, NH, NH, NH, DIM, INNER, 0, FLAG);
        gemm_t_kernel<<<dim3(12, 3), 256, 0, stream>>>((const short*)FFC1, (const short*)FCW2T,
            fcb2, fcb2, fcb2, NE, NE, NE, DIM, INNER, 0, FLAG);
    } else {
        dim3 gh(12, 24), ge(12, 3), gf1(48, 24), gf1e(48, 3);
        gemm_kernel<<<gf1, 256, 0, stream>>>((const short*)Vb, ffw1, ffb1, FF1, TOTAL, INNER, DIM, 1, FLAG);
        gemm_kernel<<<gf1e, 256, 0, stream>>>((const short*)EVb, fcw1, fcb1, FFC1, ENCR, INNER, DIM, 1, FLAG);
        gemm_kernel<<<gh, 256, 0, stream>>>((const short*)FF1, ffw2, ffb2, NH, TOTAL, DIM, INNER, 0, FLAG);
        gemm_kernel<<<ge, 256, 0, stream>>>((const short*)FFC1, fcw2, fcb2, NE, ENCR, DIM, INNER, 0, FLAG);
    }

    // 10. gated residual #2 -> outputs (e first, then h)
    resid_kernel<<<(ENCR * DIM) / 256, 256, 0, stream>>>(EKb, NE, EC, 5, 1, d_out, 0, 0, 1, FLAG);
    resid_kernel<<<(TOTAL * DIM) / 256, 256, 0, stream>>>(Kb, NH, E6, 5, 0, d_out,
                                                          (size_t)ENCR * DIM, 0, 1, FLAG);
}

// Round 2
// 1467.948 us; speedup vs baseline: 1.0454x; 1.0454x over previous
//
#include <hip/hip_runtime.h>
#include <hip/hip_bf16.h>

typedef __hip_bfloat16 bf16;
typedef short s16x8 __attribute__((ext_vector_type(8)));
typedef float f32x4 __attribute__((ext_vector_type(4)));

#define DIM   1536
#define HEADS 24
#define HD    64
#define TOTAL 3072
#define ENCR  384
#define INNER 6144
#define SIX   9216

// ---- dtype-agnostic loads: flag==1 -> inputs are float32, flag==0 -> bf16
__device__ __forceinline__ float ldf(const void* p, size_t i, int f) {
    return f ? ((const float*)p)[i]
             : __bfloat162float(((const bf16*)p)[i]);
}
__device__ __forceinline__ short f2s(float v) {
    bf16 b = __float2bfloat16(v);
    short s; __builtin_memcpy(&s, &b, 2); return s;
}
__device__ __forceinline__ s16x8 ldb8(const void* B, size_t i, int f) {
    s16x8 r;
    if (f) {
        const float4* p = (const float4*)((const float*)B + i);
        float4 x = p[0], y = p[1];
        r[0]=f2s(x.x); r[1]=f2s(x.y); r[2]=f2s(x.z); r[3]=f2s(x.w);
        r[4]=f2s(y.x); r[5]=f2s(y.y); r[6]=f2s(y.z); r[7]=f2s(y.w);
    } else {
        r = *(const s16x8*)((const short*)B + i);
    }
    return r;
}
// async global->LDS, 16B per lane; lds base must be wave-uniform
__device__ __forceinline__ void gld16(const void* g, void* l) {
    __builtin_amdgcn_global_load_lds(
        (const __attribute__((address_space(1))) unsigned int*)g,
        (__attribute__((address_space(3))) unsigned int*)l, 16, 0, 0);
}

// ---------------- probe: detect input dtype (bf16 vs f32-as-shorts)
__global__ __launch_bounds__(256) void probe_kernel(const unsigned short* __restrict__ w,
                                                    int* __restrict__ flag) {
    __shared__ int cnt;
    if (threadIdx.x == 0) cnt = 0;
    __syncthreads();
    int local = 0;
    for (int i = threadIdx.x; i < 65536; i += 256) {
        unsigned short u = w[i];
        if (((u >> 7) & 0xFF) == 0xFF) local++;
    }
    atomicAdd(&cnt, local);
    __syncthreads();
    if (threadIdx.x == 0) flag[0] = (cnt > 0) ? 1 : 0;
}

// ---------------------------------------------------------------- silu(temb)
__global__ __launch_bounds__(256) void silu_kernel(const void* __restrict__ temb,
                                                   float* __restrict__ sact,
                                                   const int* __restrict__ flag) {
    int f = flag[0];
    int i = blockIdx.x * 256 + threadIdx.x;
    float x = ldf(temb, i, f);
    sact[i] = x / (1.f + __expf(-x));
}

// -------------------------------------------- e6 = silu(temb) @ W + b (3x9216)
__global__ __launch_bounds__(256) void ada_kernel(const float* __restrict__ sact,
                                                  const void* __restrict__ W,
                                                  const void* __restrict__ bias,
                                                  float* __restrict__ out,
                                                  const int* __restrict__ flag) {
    int f = flag[0];
    __shared__ float red[3][4][64];
    int c   = threadIdx.x & 63;
    int col = blockIdx.x * 64 + c;
    int kq  = threadIdx.x >> 6;
    float a0 = 0.f, a1 = 0.f, a2 = 0.f;
    for (int k = kq * 384; k < kq * 384 + 384; ++k) {
        float wv = ldf(W, (size_t)k * SIX + col, f);
        a0 += sact[k] * wv;
        a1 += sact[1536 + k] * wv;
        a2 += sact[3072 + k] * wv;
    }
    red[0][kq][c] = a0; red[1][kq][c] = a1; red[2][kq][c] = a2;
    __syncthreads();
    if (kq < 3) {
        float s = red[kq][0][c] + red[kq][1][c] + red[kq][2][c] + red[kq][3][c]
                + ldf(bias, col, f);
        out[(size_t)kq * SIX + col] = s;
    }
}

// ------------------------- LayerNorm + AdaLN modulate
__global__ __launch_bounds__(256) void ln_mod_kernel(const void* __restrict__ x,
                                                     const float* __restrict__ ada,
                                                     bf16* __restrict__ out,
                                                     int shift_sel, int scale_sel,
                                                     int is_enc, int x_dual,
                                                     const int* __restrict__ flag) {
    int f = x_dual ? flag[0] : 0;
    __shared__ float r1[256], r2[256];
    int t = blockIdx.x, tid = threadIdx.x;
    int stage = is_enc ? (t >> 7) : (t < 512 ? 0 : (t < 1536 ? 1 : 2));
    float v[6]; float s = 0.f, s2 = 0.f;
#pragma unroll
    for (int i = 0; i < 6; ++i) {
        float a = ldf(x, (size_t)t * DIM + tid + i * 256, f);
        v[i] = a; s += a; s2 += a * a;
    }
    r1[tid] = s; r2[tid] = s2;
    __syncthreads();
    for (int st = 128; st; st >>= 1) {
        if (tid < st) { r1[tid] += r1[tid + st]; r2[tid] += r2[tid + st]; }
        __syncthreads();
    }
    float mean = r1[0] * (1.f / 1536.f);
    float var  = fmaxf(r2[0] * (1.f / 1536.f) - mean * mean, 0.f);
    float inv  = rsqrtf(var + 1e-6f);
    const float* ab = ada + (size_t)stage * SIX;
#pragma unroll
    for (int i = 0; i < 6; ++i) {
        int c = tid + i * 256;
        float sc = ab[scale_sel * DIM + c];
        float sh = ab[shift_sel * DIM + c];
        out[(size_t)t * DIM + c] = __float2bfloat16((v[i] - mean) * inv * (1.f + sc) + sh);
    }
}

// ---------- fused: res = base + gate*delta (store), then LN(res)+modulate -> out
__global__ __launch_bounds__(256) void resid_ln_kernel(const void* __restrict__ base,
                                                       const bf16* __restrict__ delta,
                                                       const float* __restrict__ ada,
                                                       int gate_sel, int shift_sel,
                                                       int scale_sel, int is_enc,
                                                       bf16* __restrict__ res,
                                                       bf16* __restrict__ out,
                                                       int base_dual,
                                                       const int* __restrict__ flag) {
    int f = base_dual ? flag[0] : 0;
    __shared__ float r1[256], r2[256];
    int t = blockIdx.x, tid = threadIdx.x;
    int stage = is_enc ? (t >> 7) : (t < 512 ? 0 : (t < 1536 ? 1 : 2));
    const float* ab = ada + (size_t)stage * SIX;
    float v[6]; float s = 0.f, s2 = 0.f;
#pragma unroll
    for (int i = 0; i < 6; ++i) {
        int c = tid + i * 256;
        size_t gi = (size_t)t * DIM + c;
        float g = ab[gate_sel * DIM + c];
        float a = ldf(base, gi, f) + g * __bfloat162float(delta[gi]);
        res[gi] = __float2bfloat16(a);
        v[i] = a; s += a; s2 += a * a;
    }
    r1[tid] = s; r2[tid] = s2;
    __syncthreads();
    for (int st = 128; st; st >>= 1) {
        if (tid < st) { r1[tid] += r1[tid + st]; r2[tid] += r2[tid + st]; }
        __syncthreads();
    }
    float mean = r1[0] * (1.f / 1536.f);
    float var  = fmaxf(r2[0] * (1.f / 1536.f) - mean * mean, 0.f);
    float inv  = rsqrtf(var + 1e-6f);
#pragma unroll
    for (int i = 0; i < 6; ++i) {
        int c = tid + i * 256;
        float sc = ab[scale_sel * DIM + c];
        float sh = ab[shift_sel * DIM + c];
        out[(size_t)t * DIM + c] = __float2bfloat16((v[i] - mean) * inv * (1.f + sc) + sh);
    }
}

// -------------------------- weight transpose: W[K][N] -> WT[N][K] (bf16 out)
// grid (N/64, K/64), block 256
__global__ __launch_bounds__(256) void wt_kernel(const void* __restrict__ W,
                                                 bf16* __restrict__ WT,
                                                 int K, int N,
                                                 const int* __restrict__ flag) {
    int f = flag[0];
    __shared__ short T[64][72];
    int n0 = blockIdx.x * 64, k0 = blockIdx.y * 64;
    int tid = threadIdx.x;
    int r = tid >> 2, c0 = (tid & 3) * 16;
#pragma unroll
    for (int i = 0; i < 16; ++i)
        T[r][c0 + i] = f2s(ldf(W, (size_t)(k0 + r) * N + n0 + c0 + i, f));
    __syncthreads();
    int n = tid >> 2, kc = (tid & 3) * 16;
    s16x8 o0, o1;
#pragma unroll
    for (int i = 0; i < 8; ++i) o0[i] = T[kc + i][n];
#pragma unroll
    for (int i = 0; i < 8; ++i) o1[i] = T[kc + 8 + i][n];
    short* orow = (short*)WT + (size_t)(n0 + n) * K + k0 + kc;
    *(s16x8*)orow = o0;
    *(s16x8*)(orow + 8) = o1;
}

// ------------------------- transposed-B MFMA GEMM, 2-phase double-buffered
// C[M, Nout(xn)] = act(A[M,K] @ Bt[N,K]^T + bias).  128x128 tile, BK=32 per
// buffer, 2 LDS buffers (32 KB total -> occupancy cap unchanged).  T3-minimum
// 2-phase schedule (m248): issue next tile's global_load_lds BEFORE computing
// the current tile; single vmcnt-drain+barrier per K-step AFTER the MFMAs, so
// HBM/L2 latency overlaps the ds_read+MFMA of the current tile.  Separate
// __shared__ objects per buffer so alias analysis can't force an early
// vmcnt(0) before the ds_reads.  XOR chunk swizzle on the global side of
// global_load_lds kills LDS read conflicts (both-sides involution, m201).
__global__ __launch_bounds__(256) void gemm_t_kernel(const short* __restrict__ A,
                                                     const short* __restrict__ Bt,
                                                     const void* __restrict__ B0,
                                                     const void* __restrict__ B1,
                                                     const void* __restrict__ B2,
                                                     bf16* __restrict__ O0,
                                                     bf16* __restrict__ O1,
                                                     bf16* __restrict__ O2,
                                                     int Nout, int K, int act,
                                                     const int* __restrict__ flag) {
    int f = flag[0];
    __shared__ __align__(16) short As0[128 * 32];
    __shared__ __align__(16) short As1[128 * 32];
    __shared__ __align__(16) short Bs0[128 * 32];
    __shared__ __align__(16) short Bs1[128 * 32];
    int tid = threadIdx.x;
    int lane = tid & 63, wid = tid >> 6;
    int wy = wid >> 1, wx = wid & 1;
    int lane15 = lane & 15, quad = lane >> 4;
    int m0 = blockIdx.y * 128, n0 = blockIdx.x * 128;
    int lr = lane >> 2, lc = lane & 3;

    f32x4 acc[4][4] = {};

    auto stage = [&](short* Ad, short* Bd, int k0) {
#pragma unroll
        for (int c = 0; c < 2; ++c) {
            int rb = wid * 32 + c * 16;
            int r = rb + lr;
            int gc = (lc - (r >> 1)) & 3;
            gld16(A  + (size_t)(m0 + r) * K + k0 + gc * 8, Ad + rb * 32);
            gld16(Bt + (size_t)(n0 + r) * K + k0 + gc * 8, Bd + rb * 32);
        }
    };
    auto compute = [&](const short* Ash, const short* Bsh) {
        s16x8 af[4], bfr[4];
#pragma unroll
        for (int i = 0; i < 4; ++i) {
            int ra = wy * 64 + i * 16 + lane15;
            af[i] = *(const s16x8*)&Ash[ra * 32 + ((quad + (ra >> 1)) & 3) * 8];
            int rb2 = wx * 64 + i * 16 + lane15;
            bfr[i] = *(const s16x8*)&Bsh[rb2 * 32 + ((quad + (rb2 >> 1)) & 3) * 8];
        }
#pragma unroll
        for (int im = 0; im < 4; ++im)
#pragma unroll
            for (int in = 0; in < 4; ++in)
                acc[im][in] = __builtin_amdgcn_mfma_f32_16x16x32_bf16(
                    af[im], bfr[in], acc[im][in], 0, 0, 0);
    };

    // K is always a multiple of 64 here (1536 or 6144) -> K/32 even.
    stage(As0, Bs0, 0);
    __syncthreads();
    for (int k0 = 0; k0 < K; k0 += 64) {
        stage(As1, Bs1, k0 + 32);            // prefetch tile t+1 (k0+32 < K always)
        compute(As0, Bs0);                   // compute tile t
        __syncthreads();                     // drain prefetch + protect buffers
        if (k0 + 64 < K) stage(As0, Bs0, k0 + 64);   // prefetch tile t+2
        compute(As1, Bs1);                   // compute tile t+1
        __syncthreads();
    }

    int sel = n0 / Nout;
    int nb = n0 - sel * Nout;
    bf16* Cout = sel == 0 ? O0 : (sel == 1 ? O1 : O2);
    const void* bs = sel == 0 ? B0 : (sel == 1 ? B1 : B2);

#pragma unroll
    for (int in = 0; in < 4; ++in) {
        int gn = nb + wx * 64 + in * 16 + lane15;
        float bsv = ldf(bs, gn, f);
#pragma unroll
        for (int im = 0; im < 4; ++im) {
#pragma unroll
            for (int r = 0; r < 4; ++r) {
                int gm = m0 + wy * 64 + im * 16 + quad * 4 + r;
                float v = acc[im][in][r] + bsv;
                if (act == 1) {
                    float u = 0.7978845608028654f * (v + 0.044715f * v * v * v);
                    float e = __expf(2.f * u);
                    v = 0.5f * v * (1.f + (1.f - 2.f / (e + 1.f)));
                }
                Cout[(size_t)gm * Nout + gn] = __float2bfloat16(v);
            }
        }
    }
}

// ---------------------------------------------------------------- legacy GEMM
// (fallback when ws is too small for transposed weights)
#define LDK 48
__global__ __launch_bounds__(256) void gemm_kernel(const short* __restrict__ A,
                                                   const void* __restrict__ B,
                                                   const void* __restrict__ bias,
                                                   bf16* __restrict__ C,
                                                   int M, int N, int K, int act,
                                                   const int* __restrict__ flag) {
    int f = flag[0];
    __shared__ __align__(16) short As[128 * LDK];
    __shared__ __align__(16) short Bs[128 * LDK];
    int tid = threadIdx.x;
    int lane = tid & 63, wid = tid >> 6;
    int wy = wid >> 1, wx = wid & 1;
    int m16 = lane & 15, quad = lane >> 4;
    int m0 = blockIdx.y * 128, n0 = blockIdx.x * 128;
    int ar0 = tid >> 2;
    int ac  = (tid & 3) * 8;
    int br0 = tid >> 4;
    int bc  = (tid & 15) * 8;
    f32x4 acc[4][4] = {};
    for (int k0 = 0; k0 < K; k0 += 32) {
        s16x8 a0 = *(const s16x8*)(A + (size_t)(m0 + ar0) * K + k0 + ac);
        s16x8 a1 = *(const s16x8*)(A + (size_t)(m0 + ar0 + 64) * K + k0 + ac);
        s16x8 b0 = ldb8(B, (size_t)(k0 + br0) * N + n0 + bc, f);
        s16x8 b1 = ldb8(B, (size_t)(k0 + br0 + 16) * N + n0 + bc, f);
        __syncthreads();
        *(s16x8*)(&As[ar0 * LDK + ac]) = a0;
        *(s16x8*)(&As[(ar0 + 64) * LDK + ac]) = a1;
#pragma unroll
        for (int i = 0; i < 8; ++i) {
            Bs[(bc + i) * LDK + br0] = b0[i];
            Bs[(bc + i) * LDK + br0 + 16] = b1[i];
        }
        __syncthreads();
        s16x8 af[4], bfr[4];
#pragma unroll
        for (int i = 0; i < 4; ++i) {
            af[i]  = *(const s16x8*)(&As[(wy * 64 + i * 16 + m16) * LDK + quad * 8]);
            bfr[i] = *(const s16x8*)(&Bs[(wx * 64 + i * 16 + m16) * LDK + quad * 8]);
        }
#pragma unroll
        for (int im = 0; im < 4; ++im)
#pragma unroll
            for (int in = 0; in < 4; ++in)
                acc[im][in] = __builtin_amdgcn_mfma_f32_16x16x32_bf16(
                    af[im], bfr[in], acc[im][in], 0, 0, 0);
    }
#pragma unroll
    for (int in = 0; in < 4; ++in) {
        int gn = n0 + wx * 64 + in * 16 + m16;
        float bsv = ldf(bias, gn, f);
#pragma unroll
        for (int im = 0; im < 4; ++im) {
#pragma unroll
            for (int r = 0; r < 4; ++r) {
                int gm = m0 + wy * 64 + im * 16 + quad * 4 + r;
                float v = acc[im][in][r] + bsv;
                if (act == 1) {
                    float u = 0.7978845608028654f * (v + 0.044715f * v * v * v);
                    float e = __expf(2.f * u);
                    v = 0.5f * v * (1.f + (1.f - 2.f / (e + 1.f)));
                }
                C[(size_t)gm * N + gn] = __float2bfloat16(v);
            }
        }
    }
}

// --------- fused per-(token,head) RMSNorm (over 64) + rotation-matrix RoPE
// 32 lanes per (token,head); lane l holds elems 2l,2l+1 -> RoPE pair in-lane.
__global__ __launch_bounds__(256) void rmsrope_kernel(bf16* __restrict__ x,
                                                      const void* __restrict__ w,
                                                      const void* __restrict__ r0,
                                                      const void* __restrict__ r1,
                                                      const void* __restrict__ r2,
                                                      int is_enc,
                                                      const int* __restrict__ flag) {
    int f = flag[0];
    int grp = blockIdx.x * 8 + (threadIdx.x >> 5);
    int l = threadIdx.x & 31;
    int t = grp / 24;
    size_t base = (size_t)grp * 64 + 2 * l;
    unsigned int u = *(const unsigned int*)((const short*)x + base);
    union { unsigned int ui; float fl; } a, b;
    a.ui = (u & 0xFFFFu) << 16;
    b.ui = u & 0xFFFF0000u;
    float x0 = a.fl, x1 = b.fl;
    float ss = x0 * x0 + x1 * x1;
#pragma unroll
    for (int off = 1; off < 32; off <<= 1) ss += __shfl_xor(ss, off);
    float inv = rsqrtf(ss * (1.f / 64.f) + 1e-6f);
    float xw0 = x0 * inv * ldf(w, 2 * l, f);
    float xw1 = x1 * inv * ldf(w, 2 * l + 1, f);
    int stage, pos;
    if (is_enc)        { stage = t >> 7; pos = t & 127; }
    else if (t < 512)  { stage = 0; pos = 128 + t; }
    else if (t < 1536) { stage = 1; pos = 128 + t - 512; }
    else               { stage = 2; pos = 128 + t - 1536; }
    const void* rt = stage == 0 ? r0 : (stage == 1 ? r1 : r2);
    size_t ro = ((size_t)pos * 32 + l) * 4;
    float c00 = ldf(rt, ro + 0, f);
    float c01 = ldf(rt, ro + 1, f);
    float c10 = ldf(rt, ro + 2, f);
    float c11 = ldf(rt, ro + 3, f);
    unsigned int o0 = (unsigned int)(unsigned short)f2s(c00 * xw0 + c01 * xw1);
    unsigned int o1 = (unsigned int)(unsigned short)f2s(c10 * xw0 + c11 * xw1);
    *(unsigned int*)((short*)x + base) = (o1 << 16) | o0;
}

// ------------------------------------- build VJt[h][d][token] per stage (for PV)
__global__ __launch_bounds__(256) void vjt_kernel(const bf16* __restrict__ Vb,
                                                  const bf16* __restrict__ EVb,
                                                  bf16* __restrict__ VJt) {
    __shared__ short T[64][72];
    int b = blockIdx.x;
    int h = b % 24, jt = b / 24;
    int s, j0, S, hbase; size_t off;
    if (jt < 10)      { s = 0; j0 = jt * 64;        S = 640;  hbase = 0;    off = 0; }
    else if (jt < 28) { s = 1; j0 = (jt - 10) * 64; S = 1152; hbase = 512;  off = (size_t)24 * 64 * 640; }
    else              { s = 2; j0 = (jt - 28) * 64; S = 1664; hbase = 1536; off = (size_t)24 * 64 * (640 + 1152); }
    int tid = threadIdx.x;
    int tr = tid >> 2, tc = (tid & 3) * 16;
    int j = j0 + tr;
    const bf16* vr = (j < 128) ? EVb + ((size_t)(s * 128 + j) * DIM + h * HD)
                               : Vb + ((size_t)(hbase + j - 128) * DIM + h * HD);
    *(s16x8*)&T[tr][tc]     = *(const s16x8*)((const short*)vr + tc);
    *(s16x8*)&T[tr][tc + 8] = *(const s16x8*)((const short*)vr + tc + 8);
    __syncthreads();
    int d = tid >> 2, c0 = (tid & 3) * 16;
    s16x8 o0, o1;
#pragma unroll
    for (int i = 0; i < 8; ++i) o0[i] = T[c0 + i][d];
#pragma unroll
    for (int i = 0; i < 8; ++i) o1[i] = T[c0 + 8 + i][d];
    short* orow = (short*)VJt + off + (size_t)(h * HD + d) * S + j0 + c0;
    *(s16x8*)orow = o0;
    *(s16x8*)(orow + 8) = o1;
}

// -------------------------------------------------- MFMA tiled flash attention
// KVBLK=64: half the barriers / softmax shuffles / P-LDS round-trips per key
// vs the KVBLK=32 version.  Block order reversed so longest-S tiles start first.
__global__ __launch_bounds__(256) void attn_mfma_kernel(const bf16* __restrict__ Qb,
                                                        const bf16* __restrict__ Kb,
                                                        const bf16* __restrict__ EQ,
                                                        const bf16* __restrict__ EK,
                                                        const bf16* __restrict__ VJt,
                                                        const int* __restrict__ encv,
                                                        bf16* __restrict__ AH,
                                                        bf16* __restrict__ AE) {
    __shared__ __align__(16) short Ks[64 * 72];
    __shared__ __align__(16) short Vt[64 * 72];
    __shared__ __align__(16) short Ps[4][16 * 72];
    int tid = threadIdx.x, wid = tid >> 6, lane = tid & 63;
    int lane15 = lane & 15, quad = lane >> 4;
    int b = (int)gridDim.x - 1 - (int)blockIdx.x;
    int h = b % 24, qt = b / 24;
    int s, qt0, S, hbase; size_t voff;
    if (qt < 10)      { s = 0; qt0 = qt;      S = 640;  hbase = 0;    voff = 0; }
    else if (qt < 28) { s = 1; qt0 = qt - 10; S = 1152; hbase = 512;  voff = (size_t)24 * 64 * 640; }
    else              { s = 2; qt0 = qt - 28; S = 1664; hbase = 1536; voff = (size_t)24 * 64 * (640 + 1152); }
    const short* vbase = (const short*)VJt + voff + (size_t)h * HD * S;
    int ev = encv[s];
    int qbase = qt0 * 64 + wid * 16;

    int q = qbase + lane15;
    const short* qrow = (q < 128)
        ? (const short*)EQ + ((size_t)(s * 128 + q) * DIM + h * HD)
        : (const short*)Qb + ((size_t)(hbase + q - 128) * DIM + h * HD);
    s16x8 qa[2];
#pragma unroll
    for (int k0 = 0; k0 < 2; ++k0) {
        s16x8 x = *(const s16x8*)(qrow + k0 * 32 + quad * 8);
#pragma unroll
        for (int i = 0; i < 8; ++i) {
            union { unsigned int u; float fl; } t;
            t.u = ((unsigned int)(unsigned short)x[i]) << 16;
            t.fl *= 0.125f;
            x[i] = (short)(t.u >> 16);
        }
        qa[k0] = x;
    }

    f32x4 o[4] = {};
    float mrun[4] = {-1e30f, -1e30f, -1e30f, -1e30f};
    float lrun[4] = {};

    int nkb = S >> 6;
    for (int kb = 0; kb < nkb; ++kb) {
        __syncthreads();
        {
            int kr = tid >> 2, kc = (tid & 3) * 16;
            int kg = kb * 64 + kr;
            const short* krow = (kg < 128)
                ? (const short*)EK + ((size_t)(s * 128 + kg) * DIM + h * HD)
                : (const short*)Kb + ((size_t)(hbase + kg - 128) * DIM + h * HD);
            *(s16x8*)&Ks[kr * 72 + kc]     = *(const s16x8*)(krow + kc);
            *(s16x8*)&Ks[kr * 72 + kc + 8] = *(const s16x8*)(krow + kc + 8);
        }
        {
            int vd = tid >> 2, vc = (tid & 3) * 16;
            const short* vrow = vbase + (size_t)vd * S + kb * 64 + vc;
            *(s16x8*)&Vt[vd * 72 + vc]     = *(const s16x8*)(vrow);
            *(s16x8*)&Vt[vd * 72 + vc + 8] = *(const s16x8*)(vrow + 8);
        }
        __syncthreads();

        f32x4 sacc[4];
        __builtin_amdgcn_s_setprio(1);
#pragma unroll
        for (int g = 0; g < 4; ++g) {
            s16x8 kf0 = *(const s16x8*)&Ks[(g * 16 + lane15) * 72 + quad * 8];
            s16x8 kf1 = *(const s16x8*)&Ks[(g * 16 + lane15) * 72 + 32 + quad * 8];
            f32x4 c = {};
            c = __builtin_amdgcn_mfma_f32_16x16x32_bf16(qa[0], kf0, c, 0, 0, 0);
            c = __builtin_amdgcn_mfma_f32_16x16x32_bf16(qa[1], kf1, c, 0, 0, 0);
            sacc[g] = c;
        }
        __builtin_amdgcn_s_setprio(0);
        if (kb == 1) {             // keys 64..127 are the only maskable ones (ev>=64)
#pragma unroll
            for (int g = 0; g < 4; ++g) {
                int keyg = 64 + g * 16 + lane15;
                if (keyg >= ev) {
#pragma unroll
                    for (int r = 0; r < 4; ++r) sacc[g][r] = -1e30f;
                }
            }
        }
        float mt[4], al[4], ps[4];
#pragma unroll
        for (int r = 0; r < 4; ++r)
            mt[r] = fmaxf(fmaxf(sacc[0][r], sacc[1][r]), fmaxf(sacc[2][r], sacc[3][r]));
#pragma unroll
        for (int off = 1; off < 16; off <<= 1)
#pragma unroll
            for (int r = 0; r < 4; ++r) mt[r] = fmaxf(mt[r], __shfl_xor(mt[r], off));
#pragma unroll
        for (int r = 0; r < 4; ++r) {
            float mn = fmaxf(mrun[r], mt[r]);
            al[r] = __expf(mrun[r] - mn);
            mrun[r] = mn;
        }
#pragma unroll
        for (int g = 0; g < 4; ++g)
#pragma unroll
            for (int r = 0; r < 4; ++r)
                sacc[g][r] = __expf(sacc[g][r] - mrun[r]);
#pragma unroll
        for (int r = 0; r < 4; ++r)
            ps[r] = (sacc[0][r] + sacc[1][r]) + (sacc[2][r] + sacc[3][r]);
#pragma unroll
        for (int off = 1; off < 16; off <<= 1)
#pragma unroll
            for (int r = 0; r < 4; ++r) ps[r] += __shfl_xor(ps[r], off);
#pragma unroll
        for (int r = 0; r < 4; ++r) lrun[r] = lrun[r] * al[r] + ps[r];
#pragma unroll
        for (int dc = 0; dc < 4; ++dc)
#pragma unroll
            for (int r = 0; r < 4; ++r) o[dc][r] *= al[r];
#pragma unroll
        for (int g = 0; g < 4; ++g)
#pragma unroll
            for (int r = 0; r < 4; ++r)
                Ps[wid][(quad * 4 + r) * 72 + g * 16 + lane15] = f2s(sacc[g][r]);
        s16x8 pa0 = *(const s16x8*)&Ps[wid][lane15 * 72 + quad * 8];
        s16x8 pa1 = *(const s16x8*)&Ps[wid][lane15 * 72 + 32 + quad * 8];
        __builtin_amdgcn_s_setprio(1);
#pragma unroll
        for (int dc = 0; dc < 4; ++dc) {
            s16x8 vf0 = *(const s16x8*)&Vt[(dc * 16 + lane15) * 72 + quad * 8];
            s16x8 vf1 = *(const s16x8*)&Vt[(dc * 16 + lane15) * 72 + 32 + quad * 8];
            o[dc] = __builtin_amdgcn_mfma_f32_16x16x32_bf16(pa0, vf0, o[dc], 0, 0, 0);
            o[dc] = __builtin_amdgcn_mfma_f32_16x16x32_bf16(pa1, vf1, o[dc], 0, 0, 0);
        }
        __builtin_amdgcn_s_setprio(0);
    }

    float invl[4];
#pragma unroll
    for (int r = 0; r < 4; ++r) invl[r] = 1.f / fmaxf(lrun[r], 1e-37f);
#pragma unroll
    for (int r = 0; r < 4; ++r) {
        int qr = qbase + quad * 4 + r;
        bf16* orow = (qr < 128)
            ? AE + ((size_t)(s * 128 + qr) * DIM + h * HD)
            : AH + ((size_t)(hbase + qr - 128) * DIM + h * HD);
#pragma unroll
        for (int dc = 0; dc < 4; ++dc)
            orow[dc * 16 + lane15] = __float2bfloat16(o[dc][r] * invl[r]);
    }
}

// --------------------- out = base + gate[stage]*delta
__global__ __launch_bounds__(256) void resid_kernel(const void* __restrict__ base,
                                                    const bf16* __restrict__ delta,
                                                    const float* __restrict__ ada,
                                                    int gate_sel, int is_enc,
                                                    void* __restrict__ out,
                                                    size_t out_off,
                                                    int base_dual, int out_dual,
                                                    const int* __restrict__ flag) {
    int bfl = base_dual ? flag[0] : 0;
    int ofl = out_dual ? flag[0] : 0;
    int gid = blockIdx.x * 256 + threadIdx.x;
    int t = gid / DIM, c = gid - t * DIM;
    int stage = is_enc ? (t >> 7) : (t < 512 ? 0 : (t < 1536 ? 1 : 2));
    float g = ada[(size_t)stage * SIX + gate_sel * DIM + c];
    float v = ldf(base, gid, bfl) + g * __bfloat162float(delta[gid]);
    if (ofl) ((float*)out)[out_off + gid] = v;
    else     ((bf16*)out)[out_off + gid] = __float2bfloat16(v);
}

extern "C" void kernel_launch(void* const* d_in, const int* in_sizes, int n_in,
                              void* d_out, int out_size, void* d_ws, size_t ws_size,
                              hipStream_t stream) {
    (void)in_sizes; (void)n_in; (void)out_size;
    const void* hid   = d_in[0];
    const void* enc   = d_in[1];
    const void* temb  = d_in[2];
    const int*  encv  = (const int*)d_in[3];
    const void* rope0 = d_in[4];
    const void* rope1 = d_in[5];
    const void* rope2 = d_in[6];
    const void* ada_w = d_in[7];  const void* ada_b = d_in[8];
    const void* ada_cw = d_in[9]; const void* ada_cb = d_in[10];
    const void* wq = d_in[11]; const void* bq = d_in[12];
    const void* wk = d_in[13]; const void* bk = d_in[14];
    const void* wv = d_in[15]; const void* bv = d_in[16];
    const void* waq = d_in[17]; const void* baq = d_in[18];
    const void* wak = d_in[19]; const void* bak = d_in[20];
    const void* wav = d_in[21]; const void* bav = d_in[22];
    const void* nq_w = d_in[23];
    const void* nk_w = d_in[24];
    const void* naq_w = d_in[25];
    const void* nak_w = d_in[26];
    const void* wo = d_in[27]; const void* bo = d_in[28];
    const void* wao = d_in[29]; const void* bao = d_in[30];
    const void* ffw1 = d_in[31]; const void* ffb1 = d_in[32];
    const void* ffw2 = d_in[33]; const void* ffb2 = d_in[34];
    const void* fcw1 = d_in[35]; const void* fcb1 = d_in[36];
    const void* fcw2 = d_in[37]; const void* fcb2 = d_in[38];

    char* ws = (char*)d_ws;
    size_t off = 0;
    auto alloc = [&](size_t bytes) {
        char* p = ws + off;
        off = (off + bytes + 255) & ~(size_t)255;
        return p;
    };
    int*   FLAG = (int*)alloc(256);
    float* SACT = (float*)alloc(3 * 1536 * 4);
    float* E6   = (float*)alloc((size_t)3 * SIX * 4);
    float* EC   = (float*)alloc((size_t)3 * SIX * 4);
    bf16* NH  = (bf16*)alloc((size_t)TOTAL * DIM * 2);
    bf16* NE  = (bf16*)alloc((size_t)ENCR * DIM * 2);
    bf16* Qb  = (bf16*)alloc((size_t)TOTAL * DIM * 2);
    bf16* Kb  = (bf16*)alloc((size_t)TOTAL * DIM * 2);
    bf16* Vb  = (bf16*)alloc((size_t)TOTAL * DIM * 2);
    bf16* EQb = (bf16*)alloc((size_t)ENCR * DIM * 2);
    bf16* EKb = (bf16*)alloc((size_t)ENCR * DIM * 2);
    bf16* EVb = (bf16*)alloc((size_t)ENCR * DIM * 2);
    bf16* VJT = (bf16*)alloc((size_t)24 * 64 * (640 + 1152 + 1664) * 2);
    bf16* FF1  = (bf16*)alloc((size_t)TOTAL * INNER * 2);
    bf16* FFC1 = (bf16*)alloc((size_t)ENCR * INNER * 2);
    // transposed weights
    const size_t SQ = (size_t)DIM * DIM;          // 1536*1536
    const size_t RC = (size_t)DIM * INNER;        // 1536*6144
    bf16* WQKVT  = (bf16*)alloc(3 * SQ * 2);      // wqT|wkT|wvT  rows 0..4607
    bf16* WAQKVT = (bf16*)alloc(3 * SQ * 2);
    bf16* WOT    = (bf16*)alloc(SQ * 2);
    bf16* WAOT   = (bf16*)alloc(SQ * 2);
    bf16* FFW1T  = (bf16*)alloc(RC * 2);          // [6144][1536]
    bf16* FFW2T  = (bf16*)alloc(RC * 2);          // [1536][6144]
    bf16* FCW1T  = (bf16*)alloc(RC * 2);
    bf16* FCW2T  = (bf16*)alloc(RC * 2);
    bool useT = (off <= ws_size);

    // 0. dtype probe
    probe_kernel<<<1, 256, 0, stream>>>((const unsigned short*)ada_w, FLAG);

    // 0b. weight transposes
    if (useT) {
        dim3 gsq(24, 24), g16(96, 24), g61(24, 96);
        wt_kernel<<<gsq, 256, 0, stream>>>(wq,  WQKVT,           DIM, DIM, FLAG);
        wt_kernel<<<gsq, 256, 0, stream>>>(wk,  WQKVT + SQ,      DIM, DIM, FLAG);
        wt_kernel<<<gsq, 256, 0, stream>>>(wv,  WQKVT + 2 * SQ,  DIM, DIM, FLAG);
        wt_kernel<<<gsq, 256, 0, stream>>>(waq, WAQKVT,          DIM, DIM, FLAG);
        wt_kernel<<<gsq, 256, 0, stream>>>(wak, WAQKVT + SQ,     DIM, DIM, FLAG);
        wt_kernel<<<gsq, 256, 0, stream>>>(wav, WAQKVT + 2 * SQ, DIM, DIM, FLAG);
        wt_kernel<<<gsq, 256, 0, stream>>>(wo,  WOT,  DIM, DIM, FLAG);
        wt_kernel<<<gsq, 256, 0, stream>>>(wao, WAOT, DIM, DIM, FLAG);
        wt_kernel<<<g16, 256, 0, stream>>>(ffw1, FFW1T, DIM, INNER, FLAG);
        wt_kernel<<<g61, 256, 0, stream>>>(ffw2, FFW2T, INNER, DIM, FLAG);
        wt_kernel<<<g16, 256, 0, stream>>>(fcw1, FCW1T, DIM, INNER, FLAG);
        wt_kernel<<<g61, 256, 0, stream>>>(fcw2, FCW2T, INNER, DIM, FLAG);
    }

    // 1. AdaLN tables
    silu_kernel<<<18, 256, 0, stream>>>(temb, SACT, FLAG);
    ada_kernel<<<144, 256, 0, stream>>>(SACT, ada_w, ada_b, E6, FLAG);
    ada_kernel<<<144, 256, 0, stream>>>(SACT, ada_cw, ada_cb, EC, FLAG);

    // 2. LN + modulate (msa)
    ln_mod_kernel<<<TOTAL, 256, 0, stream>>>(hid, E6, NH, 0, 1, 0, 1, FLAG);
    ln_mod_kernel<<<ENCR, 256, 0, stream>>>(enc, EC, NE, 0, 1, 1, 1, FLAG);

    // 3. QKV projections
    if (useT) {
        gemm_t_kernel<<<dim3(36, 24), 256, 0, stream>>>((const short*)NH, (const short*)WQKVT,
            bq, bk, bv, Qb, Kb, Vb, DIM, DIM, 0, FLAG);
        gemm_t_kernel<<<dim3(36, 3), 256, 0, stream>>>((const short*)NE, (const short*)WAQKVT,
            baq, bak, bav, EQb, EKb, EVb, DIM, DIM, 0, FLAG);
    } else {
        dim3 gh(12, 24), ge(12, 3);
        gemm_kernel<<<gh, 256, 0, stream>>>((const short*)NH, wq, bq, Qb, TOTAL, DIM, DIM, 0, FLAG);
        gemm_kernel<<<gh, 256, 0, stream>>>((const short*)NH, wk, bk, Kb, TOTAL, DIM, DIM, 0, FLAG);
        gemm_kernel<<<gh, 256, 0, stream>>>((const short*)NH, wv, bv, Vb, TOTAL, DIM, DIM, 0, FLAG);
        gemm_kernel<<<ge, 256, 0, stream>>>((const short*)NE, waq, baq, EQb, ENCR, DIM, DIM, 0, FLAG);
        gemm_kernel<<<ge, 256, 0, stream>>>((const short*)NE, wak, bak, EKb, ENCR, DIM, DIM, 0, FLAG);
        gemm_kernel<<<ge, 256, 0, stream>>>((const short*)NE, wav, bav, EVb, ENCR, DIM, DIM, 0, FLAG);
    }

    // 4. fused per-head RMSNorm + RoPE on q/k
    rmsrope_kernel<<<(TOTAL * HEADS) / 8, 256, 0, stream>>>(Qb, nq_w, rope0, rope1, rope2, 0, FLAG);
    rmsrope_kernel<<<(TOTAL * HEADS) / 8, 256, 0, stream>>>(Kb, nk_w, rope0, rope1, rope2, 0, FLAG);
    rmsrope_kernel<<<(ENCR * HEADS) / 8, 256, 0, stream>>>(EQb, naq_w, rope0, rope1, rope2, 1, FLAG);
    rmsrope_kernel<<<(ENCR * HEADS) / 8, 256, 0, stream>>>(EKb, nak_w, rope0, rope1, rope2, 1, FLAG);

    // 4b. V joint-transpose for PV B-fragments
    vjt_kernel<<<1296, 256, 0, stream>>>(Vb, EVb, VJT);

    // 5. MFMA flash attention (writes ATT_H->NH, ATT_E->NE)
    attn_mfma_kernel<<<1296, 256, 0, stream>>>(Qb, Kb, EQb, EKb, VJT, encv, NH, NE);

    // 6. output projections (PROJ_H->Qb, PROJ_E->EQb)
    if (useT) {
        gemm_t_kernel<<<dim3(12, 24), 256, 0, stream>>>((const short*)NH, (const short*)WOT,
            bo, bo, bo, Qb, Qb, Qb, DIM, DIM, 0, FLAG);
        gemm_t_kernel<<<dim3(12, 3), 256, 0, stream>>>((const short*)NE, (const short*)WAOT,
            bao, bao, bao, EQb, EQb, EQb, DIM, DIM, 0, FLAG);
    } else {
        dim3 gh(12, 24), ge(12, 3);
        gemm_kernel<<<gh, 256, 0, stream>>>((const short*)NH, wo, bo, Qb, TOTAL, DIM, DIM, 0, FLAG);
        gemm_kernel<<<ge, 256, 0, stream>>>((const short*)NE, wao, bao, EQb, ENCR, DIM, DIM, 0, FLAG);
    }

    // 7+8. fused gated residual #1 + LN + modulate (mlp)
    //      hidden: res->Kb, ln_mod->Vb ; enc: res->EKb, ln_mod->EVb
    resid_ln_kernel<<<TOTAL, 256, 0, stream>>>(hid, Qb, E6, 2, 3, 4, 0, Kb, Vb, 1, FLAG);
    resid_ln_kernel<<<ENCR, 256, 0, stream>>>(enc, EQb, EC, 2, 3, 4, 1, EKb, EVb, 1, FLAG);

    // 9. FFN
    if (useT) {
        gemm_t_kernel<<<dim3(48, 24), 256, 0, stream>>>((const short*)Vb, (const short*)FFW1T,
            ffb1, ffb1, ffb1, FF1, FF1, FF1, INNER, DIM, 1, FLAG);
        gemm_t_kernel<<<dim3(48, 3), 256, 0, stream>>>((const short*)EVb, (const short*)FCW1T,
            fcb1, fcb1, fcb1, FFC1, FFC1, FFC1, INNER, DIM, 1, FLAG);
        gemm_t_kernel<<<dim3(12, 24), 256, 0, stream>>>((const short*)FF1, (const short*)FFW2T,
            ffb2, ffb2, ffb2, NH, NH, NH, DIM, INNER, 0, FLAG);
        gemm_t_kernel<<<dim3(12, 3), 256, 0, stream>>>((const short*)FFC1, (const short*)FCW2T,
            fcb2, fcb2, fcb2, NE, NE, NE, DIM, INNER, 0, FLAG);
    } else {
        dim3 gh(12, 24), ge(12, 3), gf1(48, 24), gf1e(48, 3);
        gemm_kernel<<<gf1, 256, 0, stream>>>((const short*)Vb, ffw1, ffb1, FF1, TOTAL, INNER, DIM, 1, FLAG);
        gemm_kernel<<<gf1e, 256, 0, stream>>>((const short*)EVb, fcw1, fcb1, FFC1, ENCR, INNER, DIM, 1, FLAG);
        gemm_kernel<<<gh, 256, 0, stream>>>((const short*)FF1, ffw2, ffb2, NH, TOTAL, DIM, INNER, 0, FLAG);
        gemm_kernel<<<ge, 256, 0, stream>>>((const short*)FFC1, fcw2, fcb2, NE, ENCR, DIM, INNER, 0, FLAG);
    }

    // 10. gated residual #2 -> outputs (e first, then h)
    resid_kernel<<<(ENCR * DIM) / 256, 256, 0, stream>>>(EKb, NE, EC, 5, 1, d_out, 0, 0, 1, FLAG);
    resid_kernel<<<(TOTAL * DIM) / 256, 256, 0, stream>>>(Kb, NH, E6, 5, 0, d_out,
                                                          (size_t)ENCR * DIM, 0, 1, FLAG);
}

// Round 4
// 1135.452 us; speedup vs baseline: 1.3516x; 1.2928x over previous
//
#include <hip/hip_runtime.h>
#include <hip/hip_bf16.h>

typedef __hip_bfloat16 bf16;
typedef short s16x8 __attribute__((ext_vector_type(8)));
typedef float f32x4 __attribute__((ext_vector_type(4)));

#define DIM   1536
#define HEADS 24
#define HD    64
#define TOTAL 3072
#define ENCR  384
#define INNER 6144
#define SIX   9216

// ---- dtype-agnostic loads: flag==1 -> inputs are float32, flag==0 -> bf16
__device__ __forceinline__ float ldf(const void* p, size_t i, int f) {
    return f ? ((const float*)p)[i]
             : __bfloat162float(((const bf16*)p)[i]);
}
__device__ __forceinline__ short f2s(float v) {
    bf16 b = __float2bfloat16(v);
    short s; __builtin_memcpy(&s, &b, 2); return s;
}
__device__ __forceinline__ s16x8 ldb8(const void* B, size_t i, int f) {
    s16x8 r;
    if (f) {
        const float4* p = (const float4*)((const float*)B + i);
        float4 x = p[0], y = p[1];
        r[0]=f2s(x.x); r[1]=f2s(x.y); r[2]=f2s(x.z); r[3]=f2s(x.w);
        r[4]=f2s(y.x); r[5]=f2s(y.y); r[6]=f2s(y.z); r[7]=f2s(y.w);
    } else {
        r = *(const s16x8*)((const short*)B + i);
    }
    return r;
}
// async global->LDS, 16B per lane; lds base must be wave-uniform
__device__ __forceinline__ void gld16(const void* g, void* l) {
    __builtin_amdgcn_global_load_lds(
        (const __attribute__((address_space(1))) unsigned int*)g,
        (__attribute__((address_space(3))) unsigned int*)l, 16, 0, 0);
}

// ---------------- probe: detect input dtype (bf16 vs f32-as-shorts)
__global__ __launch_bounds__(256) void probe_kernel(const unsigned short* __restrict__ w,
                                                    int* __restrict__ flag) {
    __shared__ int cnt;
    if (threadIdx.x == 0) cnt = 0;
    __syncthreads();
    int local = 0;
    for (int i = threadIdx.x; i < 65536; i += 256) {
        unsigned short u = w[i];
        if (((u >> 7) & 0xFF) == 0xFF) local++;
    }
    atomicAdd(&cnt, local);
    __syncthreads();
    if (threadIdx.x == 0) flag[0] = (cnt > 0) ? 1 : 0;
}

// ---------------------------------------------------------------- silu(temb)
__global__ __launch_bounds__(256) void silu_kernel(const void* __restrict__ temb,
                                                   float* __restrict__ sact,
                                                   const int* __restrict__ flag) {
    int f = flag[0];
    int i = blockIdx.x * 256 + threadIdx.x;
    float x = ldf(temb, i, f);
    sact[i] = x / (1.f + __expf(-x));
}

// -------------------- e6 = silu(temb) @ W + b (3x9216), both tables in one grid
__global__ __launch_bounds__(256) void ada_kernel(const float* __restrict__ sact,
                                                  const void* __restrict__ W1,
                                                  const void* __restrict__ b1,
                                                  float* __restrict__ o1,
                                                  const void* __restrict__ W2,
                                                  const void* __restrict__ b2,
                                                  float* __restrict__ o2,
                                                  const int* __restrict__ flag) {
    int f = flag[0];
    __shared__ float red[3][4][64];
    int bx = blockIdx.x;
    const void* W; const void* bias; float* out;
    if (bx < 144) { W = W1; bias = b1; out = o1; }
    else          { W = W2; bias = b2; out = o2; bx -= 144; }
    int c   = threadIdx.x & 63;
    int col = bx * 64 + c;
    int kq  = threadIdx.x >> 6;
    float a0 = 0.f, a1 = 0.f, a2 = 0.f;
    for (int k = kq * 384; k < kq * 384 + 384; ++k) {
        float wv = ldf(W, (size_t)k * SIX + col, f);
        a0 += sact[k] * wv;
        a1 += sact[1536 + k] * wv;
        a2 += sact[3072 + k] * wv;
    }
    red[0][kq][c] = a0; red[1][kq][c] = a1; red[2][kq][c] = a2;
    __syncthreads();
    if (kq < 3) {
        float s = red[kq][0][c] + red[kq][1][c] + red[kq][2][c] + red[kq][3][c]
                + ldf(bias, col, f);
        out[(size_t)kq * SIX + col] = s;
    }
}

// ------------------------- LayerNorm + AdaLN modulate (hid + enc in one grid)
__global__ __launch_bounds__(256) void ln_mod_kernel(const void* __restrict__ xh,
                                                     const void* __restrict__ xe,
                                                     const float* __restrict__ adaH,
                                                     const float* __restrict__ adaE,
                                                     bf16* __restrict__ outh,
                                                     bf16* __restrict__ oute,
                                                     const int* __restrict__ flag) {
    int f = flag[0];
    __shared__ float r1[256], r2[256];
    int t = blockIdx.x, tid = threadIdx.x;
    const void* x; bf16* out; const float* ada; int stage;
    if (t < TOTAL) { x = xh; out = outh; ada = adaH; stage = t < 512 ? 0 : (t < 1536 ? 1 : 2); }
    else           { t -= TOTAL; x = xe; out = oute; ada = adaE; stage = t >> 7; }
    float v[6]; float s = 0.f, s2 = 0.f;
#pragma unroll
    for (int i = 0; i < 6; ++i) {
        float a = ldf(x, (size_t)t * DIM + tid + i * 256, f);
        v[i] = a; s += a; s2 += a * a;
    }
    r1[tid] = s; r2[tid] = s2;
    __syncthreads();
    for (int st = 128; st; st >>= 1) {
        if (tid < st) { r1[tid] += r1[tid + st]; r2[tid] += r2[tid + st]; }
        __syncthreads();
    }
    float mean = r1[0] * (1.f / 1536.f);
    float var  = fmaxf(r2[0] * (1.f / 1536.f) - mean * mean, 0.f);
    float inv  = rsqrtf(var + 1e-6f);
    const float* ab = ada + (size_t)stage * SIX;
#pragma unroll
    for (int i = 0; i < 6; ++i) {
        int c = tid + i * 256;
        float sc = ab[1 * DIM + c];
        float sh = ab[0 * DIM + c];
        out[(size_t)t * DIM + c] = __float2bfloat16((v[i] - mean) * inv * (1.f + sc) + sh);
    }
}

// -- fused: res = base + gate*delta (store), then LN(res)+modulate -> out (both sides)
__global__ __launch_bounds__(256) void resid_ln_kernel(const void* __restrict__ bh,
                                                       const bf16* __restrict__ dh,
                                                       const float* __restrict__ adaH,
                                                       bf16* __restrict__ resh,
                                                       bf16* __restrict__ outh,
                                                       const void* __restrict__ be,
                                                       const bf16* __restrict__ de,
                                                       const float* __restrict__ adaE,
                                                       bf16* __restrict__ rese,
                                                       bf16* __restrict__ oute,
                                                       const int* __restrict__ flag) {
    int f = flag[0];
    __shared__ float r1[256], r2[256];
    int t = blockIdx.x, tid = threadIdx.x;
    const void* base; const bf16* delta; const float* ada; bf16* res; bf16* out; int stage;
    if (t < TOTAL) { base = bh; delta = dh; ada = adaH; res = resh; out = outh;
                     stage = t < 512 ? 0 : (t < 1536 ? 1 : 2); }
    else           { t -= TOTAL; base = be; delta = de; ada = adaE; res = rese; out = oute;
                     stage = t >> 7; }
    const float* ab = ada + (size_t)stage * SIX;
    float v[6]; float s = 0.f, s2 = 0.f;
#pragma unroll
    for (int i = 0; i < 6; ++i) {
        int c = tid + i * 256;
        size_t gi = (size_t)t * DIM + c;
        float g = ab[2 * DIM + c];
        float a = ldf(base, gi, f) + g * __bfloat162float(delta[gi]);
        res[gi] = __float2bfloat16(a);
        v[i] = a; s += a; s2 += a * a;
    }
    r1[tid] = s; r2[tid] = s2;
    __syncthreads();
    for (int st = 128; st; st >>= 1) {
        if (tid < st) { r1[tid] += r1[tid + st]; r2[tid] += r2[tid + st]; }
        __syncthreads();
    }
    float mean = r1[0] * (1.f / 1536.f);
    float var  = fmaxf(r2[0] * (1.f / 1536.f) - mean * mean, 0.f);
    float inv  = rsqrtf(var + 1e-6f);
#pragma unroll
    for (int i = 0; i < 6; ++i) {
        int c = tid + i * 256;
        float sc = ab[4 * DIM + c];
        float sh = ab[3 * DIM + c];
        out[(size_t)t * DIM + c] = __float2bfloat16((v[i] - mean) * inv * (1.f + sc) + sh);
    }
}

// -------------------------- weight transpose bodies
__device__ __forceinline__ void wt_body(const void* W, bf16* WT, int K, int N, int f) {
    __shared__ short T[64][72];
    int n0 = blockIdx.x * 64, k0 = blockIdx.y * 64;
    int tid = threadIdx.x;
    int r = tid >> 2, c0 = (tid & 3) * 16;
#pragma unroll
    for (int i = 0; i < 16; ++i)
        T[r][c0 + i] = f2s(ldf(W, (size_t)(k0 + r) * N + n0 + c0 + i, f));
    __syncthreads();
    int n = tid >> 2, kc = (tid & 3) * 16;
    s16x8 o0, o1;
#pragma unroll
    for (int i = 0; i < 8; ++i) o0[i] = T[kc + i][n];
#pragma unroll
    for (int i = 0; i < 8; ++i) o1[i] = T[kc + 8 + i][n];
    short* orow = (short*)WT + (size_t)(n0 + n) * K + k0 + kc;
    *(s16x8*)orow = o0;
    *(s16x8*)(orow + 8) = o1;
}

// 8 square (DIMxDIM) transposes in one launch, z selects
__global__ __launch_bounds__(256) void wt8_kernel(const void* s0, const void* s1,
                                                  const void* s2, const void* s3,
                                                  const void* s4, const void* s5,
                                                  const void* s6, const void* s7,
                                                  bf16* d0, bf16* d1, bf16* d2, bf16* d3,
                                                  bf16* d4, bf16* d5, bf16* d6, bf16* d7,
                                                  const int* __restrict__ flag) {
    const void* W; bf16* WT;
    switch (blockIdx.z) {
        case 0: W = s0; WT = d0; break;  case 1: W = s1; WT = d1; break;
        case 2: W = s2; WT = d2; break;  case 3: W = s3; WT = d3; break;
        case 4: W = s4; WT = d4; break;  case 5: W = s5; WT = d5; break;
        case 6: W = s6; WT = d6; break;  default: W = s7; WT = d7; break;
    }
    wt_body(W, WT, DIM, DIM, flag[0]);
}

// 2 rectangular transposes in one launch (same K,N), z selects
__global__ __launch_bounds__(256) void wt2_kernel(const void* s0, const void* s1,
                                                  bf16* d0, bf16* d1, int K, int N,
                                                  const int* __restrict__ flag) {
    const void* W = blockIdx.z ? s1 : s0;
    bf16* WT = blockIdx.z ? d1 : d0;
    wt_body(W, WT, K, N, flag[0]);
}

// ------------------------- transposed-B MFMA GEMM, depth-2 counted-vmcnt pipeline
// C[M, Nout(xn)] = act(A[M,K] @ Bt[N,K]^T + bias).  128x128 tile, BK=32 per
// buffer, 3 distinct LDS buffer pairs (48 KB).  Schedule per K-step t:
//   stage(t+2) -> s_waitcnt vmcnt(8)  [= stages t+1,t+2 still in flight,
//   stage(t) complete] -> s_barrier -> ds_read+MFMA on buf(t) ->
//   lgkmcnt(0) -> s_barrier.  Loads get ~2 compute phases to fly; vmcnt is
//   never drained to 0 in steady state (T4).  Buffers are separate named
//   __shared__ objects with static indices so the waitcnt legalizer can
//   disambiguate pending global_load_lds from current ds_reads.
// Handles hidden-side (by<yh) and enc-side (by>=yh) problems in one grid, and
// applies the m204 bijective XCD chunk swizzle for L2 panel locality.
__global__ __launch_bounds__(256) void gemm_t_kernel(const short* __restrict__ Ah,
                                                     const short* __restrict__ Ae,
                                                     const short* __restrict__ Bth,
                                                     const short* __restrict__ Bte,
                                                     const void* Bh0, const void* Bh1, const void* Bh2,
                                                     const void* Be0, const void* Be1, const void* Be2,
                                                     bf16* Oh0, bf16* Oh1, bf16* Oh2,
                                                     bf16* Oe0, bf16* Oe1, bf16* Oe2,
                                                     int yh, int Nout, int K, int act,
                                                     const int* __restrict__ flag) {
    int f = flag[0];
    __shared__ __align__(16) short As0[128 * 32];
    __shared__ __align__(16) short As1[128 * 32];
    __shared__ __align__(16) short As2[128 * 32];
    __shared__ __align__(16) short Bs0[128 * 32];
    __shared__ __align__(16) short Bs1[128 * 32];
    __shared__ __align__(16) short Bs2[128 * 32];
    int tid = threadIdx.x;
    int lane = tid & 63, wid = tid >> 6;
    int wy = wid >> 1, wx = wid & 1;
    int lane15 = lane & 15, quad = lane >> 4;

    // bijective XCD chunk swizzle (m204): contiguous logical tiles per XCD
    int gx = gridDim.x;
    int nwg = gx * gridDim.y;
    int orig = blockIdx.y * gx + blockIdx.x;
    int q = nwg >> 3, r = nwg & 7;
    int x8 = orig & 7, o8 = orig >> 3;
    int wg = (x8 < r) ? x8 * (q + 1) + o8 : r * (q + 1) + (x8 - r) * q + o8;
    int bx = wg % gx, by = wg / gx;

    const short* A; const short* Bt; int m0;
    const void *b0, *b1, *b2; bf16 *o0, *o1, *o2;
    if (by < yh) { A = Ah; Bt = Bth; m0 = by * 128;
                   b0 = Bh0; b1 = Bh1; b2 = Bh2; o0 = Oh0; o1 = Oh1; o2 = Oh2; }
    else         { A = Ae; Bt = Bte; m0 = (by - yh) * 128;
                   b0 = Be0; b1 = Be1; b2 = Be2; o0 = Oe0; o1 = Oe1; o2 = Oe2; }
    int n0 = bx * 128;
    int lr = lane >> 2, lc = lane & 3;

    f32x4 acc[4][4] = {};

    auto stage = [&](short* Ad, short* Bd, int k0) {
#pragma unroll
        for (int c = 0; c < 2; ++c) {
            int rb = wid * 32 + c * 16;
            int rr = rb + lr;
            int gc = (lc - (rr >> 1)) & 3;
            gld16(A  + (size_t)(m0 + rr) * K + k0 + gc * 8, Ad + rb * 32);
            gld16(Bt + (size_t)(n0 + rr) * K + k0 + gc * 8, Bd + rb * 32);
        }
    };
    auto compute = [&](const short* Ash, const short* Bsh) {
        s16x8 af[4], bfr[4];
#pragma unroll
        for (int i = 0; i < 4; ++i) {
            int ra = wy * 64 + i * 16 + lane15;
            af[i] = *(const s16x8*)&Ash[ra * 32 + ((quad + (ra >> 1)) & 3) * 8];
            int rb2 = wx * 64 + i * 16 + lane15;
            bfr[i] = *(const s16x8*)&Bsh[rb2 * 32 + ((quad + (rb2 >> 1)) & 3) * 8];
        }
#pragma unroll
        for (int im = 0; im < 4; ++im)
#pragma unroll
            for (int in = 0; in < 4; ++in)
                acc[im][in] = __builtin_amdgcn_mfma_f32_16x16x32_bf16(
                    af[im], bfr[in], acc[im][in], 0, 0, 0);
    };
    int nt = K >> 5;   // 48 or 192; always divisible by 3, always >= 3
    auto step = [&](const short* Ac, const short* Bc, short* An, short* Bn, int tt) {
        int nx = tt + 2;
        if (nx < nt) {
            stage(An, Bn, nx << 5);
            asm volatile("s_waitcnt vmcnt(8)" ::: "memory");
        } else if (tt + 1 < nt) {
            asm volatile("s_waitcnt vmcnt(4)" ::: "memory");
        } else {
            asm volatile("s_waitcnt vmcnt(0)" ::: "memory");
        }
        __builtin_amdgcn_s_barrier();
        compute(Ac, Bc);
        asm volatile("s_waitcnt lgkmcnt(0)" ::: "memory");
        __builtin_amdgcn_s_barrier();
    };

    stage(As0, Bs0, 0);
    stage(As1, Bs1, 32);
    for (int t = 0; t < nt; t += 3) {
        step(As0, Bs0, As2, Bs2, t);
        step(As1, Bs1, As0, Bs0, t + 1);
        step(As2, Bs2, As1, Bs1, t + 2);
    }

    int sel = n0 / Nout;
    int nb = n0 - sel * Nout;
    bf16* Cout = sel == 0 ? o0 : (sel == 1 ? o1 : o2);
    const void* bs = sel == 0 ? b0 : (sel == 1 ? b1 : b2);

#pragma unroll
    for (int in = 0; in < 4; ++in) {
        int gn = nb + wx * 64 + in * 16 + lane15;
        float bsv = ldf(bs, gn, f);
#pragma unroll
        for (int im = 0; im < 4; ++im) {
#pragma unroll
            for (int rr = 0; rr < 4; ++rr) {
                int gm = m0 + wy * 64 + im * 16 + quad * 4 + rr;
                float v = acc[im][in][rr] + bsv;
                if (act == 1) {
                    float u = 0.7978845608028654f * (v + 0.044715f * v * v * v);
                    float e = __expf(2.f * u);
                    v = 0.5f * v * (1.f + (1.f - 2.f / (e + 1.f)));
                }
                Cout[(size_t)gm * Nout + gn] = __float2bfloat16(v);
            }
        }
    }
}

// ---------------------------------------------------------------- legacy GEMM
// (fallback when ws is too small for transposed weights)
#define LDK 48
__global__ __launch_bounds__(256) void gemm_kernel(const short* __restrict__ A,
                                                   const void* __restrict__ B,
                                                   const void* __restrict__ bias,
                                                   bf16* __restrict__ C,
                                                   int M, int N, int K, int act,
                                                   const int* __restrict__ flag) {
    int f = flag[0];
    __shared__ __align__(16) short As[128 * LDK];
    __shared__ __align__(16) short Bs[128 * LDK];
    int tid = threadIdx.x;
    int lane = tid & 63, wid = tid >> 6;
    int wy = wid >> 1, wx = wid & 1;
    int m16 = lane & 15, quad = lane >> 4;
    int m0 = blockIdx.y * 128, n0 = blockIdx.x * 128;
    int ar0 = tid >> 2;
    int ac  = (tid & 3) * 8;
    int br0 = tid >> 4;
    int bc  = (tid & 15) * 8;
    f32x4 acc[4][4] = {};
    for (int k0 = 0; k0 < K; k0 += 32) {
        s16x8 a0 = *(const s16x8*)(A + (size_t)(m0 + ar0) * K + k0 + ac);
        s16x8 a1 = *(const s16x8*)(A + (size_t)(m0 + ar0 + 64) * K + k0 + ac);
        s16x8 b0 = ldb8(B, (size_t)(k0 + br0) * N + n0 + bc, f);
        s16x8 b1 = ldb8(B, (size_t)(k0 + br0 + 16) * N + n0 + bc, f);
        __syncthreads();
        *(s16x8*)(&As[ar0 * LDK + ac]) = a0;
        *(s16x8*)(&As[(ar0 + 64) * LDK + ac]) = a1;
#pragma unroll
        for (int i = 0; i < 8; ++i) {
            Bs[(bc + i) * LDK + br0] = b0[i];
            Bs[(bc + i) * LDK + br0 + 16] = b1[i];
        }
        __syncthreads();
        s16x8 af[4], bfr[4];
#pragma unroll
        for (int i = 0; i < 4; ++i) {
            af[i]  = *(const s16x8*)(&As[(wy * 64 + i * 16 + m16) * LDK + quad * 8]);
            bfr[i] = *(const s16x8*)(&Bs[(wx * 64 + i * 16 + m16) * LDK + quad * 8]);
        }
#pragma unroll
        for (int im = 0; im < 4; ++im)
#pragma unroll
            for (int in = 0; in < 4; ++in)
                acc[im][in] = __builtin_amdgcn_mfma_f32_16x16x32_bf16(
                    af[im], bfr[in], acc[im][in], 0, 0, 0);
    }
#pragma unroll
    for (int in = 0; in < 4; ++in) {
        int gn = n0 + wx * 64 + in * 16 + m16;
        float bsv = ldf(bias, gn, f);
#pragma unroll
        for (int im = 0; im < 4; ++im) {
#pragma unroll
            for (int r = 0; r < 4; ++r) {
                int gm = m0 + wy * 64 + im * 16 + quad * 4 + r;
                float v = acc[im][in][r] + bsv;
                if (act == 1) {
                    float u = 0.7978845608028654f * (v + 0.044715f * v * v * v);
                    float e = __expf(2.f * u);
                    v = 0.5f * v * (1.f + (1.f - 2.f / (e + 1.f)));
                }
                C[(size_t)gm * N + gn] = __float2bfloat16(v);
            }
        }
    }
}

// --------- fused per-(token,head) RMSNorm (over 64) + rotation-matrix RoPE
// All four tensors (Q,K,EQ,EK) in one grid; 32 lanes per (token,head).
__global__ __launch_bounds__(256) void rmsrope_kernel(bf16* __restrict__ Qb,
                                                      bf16* __restrict__ Kb,
                                                      bf16* __restrict__ EQb,
                                                      bf16* __restrict__ EKb,
                                                      const void* __restrict__ nq,
                                                      const void* __restrict__ nk,
                                                      const void* __restrict__ naq,
                                                      const void* __restrict__ nak,
                                                      const void* __restrict__ r0,
                                                      const void* __restrict__ r1,
                                                      const void* __restrict__ r2,
                                                      const int* __restrict__ flag) {
    int f = flag[0];
    int bid = blockIdx.x;
    bf16* x; const void* w; int is_enc;
    if (bid < 9216)       { x = Qb;  w = nq;  is_enc = 0; }
    else if (bid < 18432) { x = Kb;  w = nk;  is_enc = 0; bid -= 9216; }
    else if (bid < 19584) { x = EQb; w = naq; is_enc = 1; bid -= 18432; }
    else                  { x = EKb; w = nak; is_enc = 1; bid -= 19584; }
    int grp = bid * 8 + (threadIdx.x >> 5);
    int l = threadIdx.x & 31;
    int t = grp / 24;
    size_t base = (size_t)grp * 64 + 2 * l;
    unsigned int u = *(const unsigned int*)((const short*)x + base);
    union { unsigned int ui; float fl; } a, b;
    a.ui = (u & 0xFFFFu) << 16;
    b.ui = u & 0xFFFF0000u;
    float x0 = a.fl, x1 = b.fl;
    float ss = x0 * x0 + x1 * x1;
#pragma unroll
    for (int off = 1; off < 32; off <<= 1) ss += __shfl_xor(ss, off);
    float inv = rsqrtf(ss * (1.f / 64.f) + 1e-6f);
    float xw0 = x0 * inv * ldf(w, 2 * l, f);
    float xw1 = x1 * inv * ldf(w, 2 * l + 1, f);
    int stage, pos;
    if (is_enc)        { stage = t >> 7; pos = t & 127; }
    else if (t < 512)  { stage = 0; pos = 128 + t; }
    else if (t < 1536) { stage = 1; pos = 128 + t - 512; }
    else               { stage = 2; pos = 128 + t - 1536; }
    const void* rt = stage == 0 ? r0 : (stage == 1 ? r1 : r2);
    size_t ro = ((size_t)pos * 32 + l) * 4;
    float c00 = ldf(rt, ro + 0, f);
    float c01 = ldf(rt, ro + 1, f);
    float c10 = ldf(rt, ro + 2, f);
    float c11 = ldf(rt, ro + 3, f);
    unsigned int q0 = (unsigned int)(unsigned short)f2s(c00 * xw0 + c01 * xw1);
    unsigned int q1 = (unsigned int)(unsigned short)f2s(c10 * xw0 + c11 * xw1);
    *(unsigned int*)((short*)x + base) = (q1 << 16) | q0;
}

// ------------------------------------- build VJt[h][d][token] per stage (for PV)
__global__ __launch_bounds__(256) void vjt_kernel(const bf16* __restrict__ Vb,
                                                  const bf16* __restrict__ EVb,
                                                  bf16* __restrict__ VJt) {
    __shared__ short T[64][72];
    int b = blockIdx.x;
    int h = b % 24, jt = b / 24;
    int s, j0, S, hbase; size_t off;
    if (jt < 10)      { s = 0; j0 = jt * 64;        S = 640;  hbase = 0;    off = 0; }
    else if (jt < 28) { s = 1; j0 = (jt - 10) * 64; S = 1152; hbase = 512;  off = (size_t)24 * 64 * 640; }
    else              { s = 2; j0 = (jt - 28) * 64; S = 1664; hbase = 1536; off = (size_t)24 * 64 * (640 + 1152); }
    int tid = threadIdx.x;
    int tr = tid >> 2, tc = (tid & 3) * 16;
    int j = j0 + tr;
    const bf16* vr = (j < 128) ? EVb + ((size_t)(s * 128 + j) * DIM + h * HD)
                               : Vb + ((size_t)(hbase + j - 128) * DIM + h * HD);
    *(s16x8*)&T[tr][tc]     = *(const s16x8*)((const short*)vr + tc);
    *(s16x8*)&T[tr][tc + 8] = *(const s16x8*)((const short*)vr + tc + 8);
    __syncthreads();
    int d = tid >> 2, c0 = (tid & 3) * 16;
    s16x8 o0, o1;
#pragma unroll
    for (int i = 0; i < 8; ++i) o0[i] = T[c0 + i][d];
#pragma unroll
    for (int i = 0; i < 8; ++i) o1[i] = T[c0 + 8 + i][d];
    short* orow = (short*)VJt + off + (size_t)(h * HD + d) * S + j0 + c0;
    *(s16x8*)orow = o0;
    *(s16x8*)(orow + 8) = o1;
}

// -------------------------------------------------- MFMA tiled flash attention
__global__ __launch_bounds__(256) void attn_mfma_kernel(const bf16* __restrict__ Qb,
                                                        const bf16* __restrict__ Kb,
                                                        const bf16* __restrict__ EQ,
                                                        const bf16* __restrict__ EK,
                                                        const bf16* __restrict__ VJt,
                                                        const int* __restrict__ encv,
                                                        bf16* __restrict__ AH,
                                                        bf16* __restrict__ AE) {
    __shared__ __align__(16) short Ks[64 * 72];
    __shared__ __align__(16) short Vt[64 * 72];
    __shared__ __align__(16) short Ps[4][16 * 72];
    int tid = threadIdx.x, wid = tid >> 6, lane = tid & 63;
    int lane15 = lane & 15, quad = lane >> 4;
    int b = (int)gridDim.x - 1 - (int)blockIdx.x;
    int h = b % 24, qt = b / 24;
    int s, qt0, S, hbase; size_t voff;
    if (qt < 10)      { s = 0; qt0 = qt;      S = 640;  hbase = 0;    voff = 0; }
    else if (qt < 28) { s = 1; qt0 = qt - 10; S = 1152; hbase = 512;  voff = (size_t)24 * 64 * 640; }
    else              { s = 2; qt0 = qt - 28; S = 1664; hbase = 1536; voff = (size_t)24 * 64 * (640 + 1152); }
    const short* vbase = (const short*)VJt + voff + (size_t)h * HD * S;
    int ev = encv[s];
    int qbase = qt0 * 64 + wid * 16;

    int q = qbase + lane15;
    const short* qrow = (q < 128)
        ? (const short*)EQ + ((size_t)(s * 128 + q) * DIM + h * HD)
        : (const short*)Qb + ((size_t)(hbase + q - 128) * DIM + h * HD);
    s16x8 qa[2];
#pragma unroll
    for (int k0 = 0; k0 < 2; ++k0) {
        s16x8 x = *(const s16x8*)(qrow + k0 * 32 + quad * 8);
#pragma unroll
        for (int i = 0; i < 8; ++i) {
            union { unsigned int u; float fl; } t;
            t.u = ((unsigned int)(unsigned short)x[i]) << 16;
            t.fl *= 0.125f;
            x[i] = (short)(t.u >> 16);
        }
        qa[k0] = x;
    }

    f32x4 o[4] = {};
    float mrun[4] = {-1e30f, -1e30f, -1e30f, -1e30f};
    float lrun[4] = {};

    int nkb = S >> 6;
    for (int kb = 0; kb < nkb; ++kb) {
        __syncthreads();
        {
            int kr = tid >> 2, kc = (tid & 3) * 16;
            int kg = kb * 64 + kr;
            const short* krow = (kg < 128)
                ? (const short*)EK + ((size_t)(s * 128 + kg) * DIM + h * HD)
                : (const short*)Kb + ((size_t)(hbase + kg - 128) * DIM + h * HD);
            *(s16x8*)&Ks[kr * 72 + kc]     = *(const s16x8*)(krow + kc);
            *(s16x8*)&Ks[kr * 72 + kc + 8] = *(const s16x8*)(krow + kc + 8);
        }
        {
            int vd = tid >> 2, vc = (tid & 3) * 16;
            const short* vrow = vbase + (size_t)vd * S + kb * 64 + vc;
            *(s16x8*)&Vt[vd * 72 + vc]     = *(const s16x8*)(vrow);
            *(s16x8*)&Vt[vd * 72 + vc + 8] = *(const s16x8*)(vrow + 8);
        }
        __syncthreads();

        f32x4 sacc[4];
        __builtin_amdgcn_s_setprio(1);
#pragma unroll
        for (int g = 0; g < 4; ++g) {
            s16x8 kf0 = *(const s16x8*)&Ks[(g * 16 + lane15) * 72 + quad * 8];
            s16x8 kf1 = *(const s16x8*)&Ks[(g * 16 + lane15) * 72 + 32 + quad * 8];
            f32x4 c = {};
            c = __builtin_amdgcn_mfma_f32_16x16x32_bf16(qa[0], kf0, c, 0, 0, 0);
            c = __builtin_amdgcn_mfma_f32_16x16x32_bf16(qa[1], kf1, c, 0, 0, 0);
            sacc[g] = c;
        }
        __builtin_amdgcn_s_setprio(0);
        if (kb == 1) {             // keys 64..127 are the only maskable ones (ev>=64)
#pragma unroll
            for (int g = 0; g < 4; ++g) {
                int keyg = 64 + g * 16 + lane15;
                if (keyg >= ev) {
#pragma unroll
                    for (int r = 0; r < 4; ++r) sacc[g][r] = -1e30f;
                }
            }
        }
        float mt[4], al[4], ps[4];
#pragma unroll
        for (int r = 0; r < 4; ++r)
            mt[r] = fmaxf(fmaxf(sacc[0][r], sacc[1][r]), fmaxf(sacc[2][r], sacc[3][r]));
#pragma unroll
        for (int off = 1; off < 16; off <<= 1)
#pragma unroll
            for (int r = 0; r < 4; ++r) mt[r] = fmaxf(mt[r], __shfl_xor(mt[r], off));
#pragma unroll
        for (int r = 0; r < 4; ++r) {
            float mn = fmaxf(mrun[r], mt[r]);
            al[r] = __expf(mrun[r] - mn);
            mrun[r] = mn;
        }
#pragma unroll
        for (int g = 0; g < 4; ++g)
#pragma unroll
            for (int r = 0; r < 4; ++r)
                sacc[g][r] = __expf(sacc[g][r] - mrun[r]);
#pragma unroll
        for (int r = 0; r < 4; ++r)
            ps[r] = (sacc[0][r] + sacc[1][r]) + (sacc[2][r] + sacc[3][r]);
#pragma unroll
        for (int off = 1; off < 16; off <<= 1)
#pragma unroll
            for (int r = 0; r < 4; ++r) ps[r] += __shfl_xor(ps[r], off);
#pragma unroll
        for (int r = 0; r < 4; ++r) lrun[r] = lrun[r] * al[r] + ps[r];
#pragma unroll
        for (int dc = 0; dc < 4; ++dc)
#pragma unroll
            for (int r = 0; r < 4; ++r) o[dc][r] *= al[r];
#pragma unroll
        for (int g = 0; g < 4; ++g)
#pragma unroll
            for (int r = 0; r < 4; ++r)
                Ps[wid][(quad * 4 + r) * 72 + g * 16 + lane15] = f2s(sacc[g][r]);
        s16x8 pa0 = *(const s16x8*)&Ps[wid][lane15 * 72 + quad * 8];
        s16x8 pa1 = *(const s16x8*)&Ps[wid][lane15 * 72 + 32 + quad * 8];
        __builtin_amdgcn_s_setprio(1);
#pragma unroll
        for (int dc = 0; dc < 4; ++dc) {
            s16x8 vf0 = *(const s16x8*)&Vt[(dc * 16 + lane15) * 72 + quad * 8];
            s16x8 vf1 = *(const s16x8*)&Vt[(dc * 16 + lane15) * 72 + 32 + quad * 8];
            o[dc] = __builtin_amdgcn_mfma_f32_16x16x32_bf16(pa0, vf0, o[dc], 0, 0, 0);
            o[dc] = __builtin_amdgcn_mfma_f32_16x16x32_bf16(pa1, vf1, o[dc], 0, 0, 0);
        }
        __builtin_amdgcn_s_setprio(0);
    }

    float invl[4];
#pragma unroll
    for (int r = 0; r < 4; ++r) invl[r] = 1.f / fmaxf(lrun[r], 1e-37f);
#pragma unroll
    for (int r = 0; r < 4; ++r) {
        int qr = qbase + quad * 4 + r;
        bf16* orow = (qr < 128)
            ? AE + ((size_t)(s * 128 + qr) * DIM + h * HD)
            : AH + ((size_t)(hbase + qr - 128) * DIM + h * HD);
#pragma unroll
        for (int dc = 0; dc < 4; ++dc)
            orow[dc * 16 + lane15] = __float2bfloat16(o[dc][r] * invl[r]);
    }
}

// --------------------- final gated residuals -> packed output [e | h]
__global__ __launch_bounds__(256) void resid_out_kernel(const bf16* __restrict__ bh,
                                                        const bf16* __restrict__ dh,
                                                        const float* __restrict__ adaH,
                                                        const bf16* __restrict__ be,
                                                        const bf16* __restrict__ de,
                                                        const float* __restrict__ adaE,
                                                        void* __restrict__ out,
                                                        const int* __restrict__ flag) {
    int ofl = flag[0];
    int bid = blockIdx.x, tid = threadIdx.x;
    float v; size_t oidx;
    if (bid < 2304) {
        int gid = bid * 256 + tid;
        int t = gid / DIM, c = gid - t * DIM;
        int st = t >> 7;
        v = __bfloat162float(be[gid]) + adaE[(size_t)st * SIX + 5 * DIM + c] * __bfloat162float(de[gid]);
        oidx = gid;
    } else {
        int gid = (bid - 2304) * 256 + tid;
        int t = gid / DIM, c = gid - t * DIM;
        int st = t < 512 ? 0 : (t < 1536 ? 1 : 2);
        v = __bfloat162float(bh[gid]) + adaH[(size_t)st * SIX + 5 * DIM + c] * __bfloat162float(dh[gid]);
        oidx = (size_t)ENCR * DIM + gid;
    }
    if (ofl) ((float*)out)[oidx] = v;
    else     ((bf16*)out)[oidx] = __float2bfloat16(v);
}

extern "C" void kernel_launch(void* const* d_in, const int* in_sizes, int n_in,
                              void* d_out, int out_size, void* d_ws, size_t ws_size,
                              hipStream_t stream) {
    (void)in_sizes; (void)n_in; (void)out_size;
    const void* hid   = d_in[0];
    const void* enc   = d_in[1];
    const void* temb  = d_in[2];
    const int*  encv  = (const int*)d_in[3];
    const void* rope0 = d_in[4];
    const void* rope1 = d_in[5];
    const void* rope2 = d_in[6];
    const void* ada_w = d_in[7];  const void* ada_b = d_in[8];
    const void* ada_cw = d_in[9]; const void* ada_cb = d_in[10];
    const void* wq = d_in[11]; const void* bq = d_in[12];
    const void* wk = d_in[13]; const void* bk = d_in[14];
    const void* wv = d_in[15]; const void* bv = d_in[16];
    const void* waq = d_in[17]; const void* baq = d_in[18];
    const void* wak = d_in[19]; const void* bak = d_in[20];
    const void* wav = d_in[21]; const void* bav = d_in[22];
    const void* nq_w = d_in[23];
    const void* nk_w = d_in[24];
    const void* naq_w = d_in[25];
    const void* nak_w = d_in[26];
    const void* wo = d_in[27]; const void* bo = d_in[28];
    const void* wao = d_in[29]; const void* bao = d_in[30];
    const void* ffw1 = d_in[31]; const void* ffb1 = d_in[32];
    const void* ffw2 = d_in[33]; const void* ffb2 = d_in[34];
    const void* fcw1 = d_in[35]; const void* fcb1 = d_in[36];
    const void* fcw2 = d_in[37]; const void* fcb2 = d_in[38];

    char* ws = (char*)d_ws;
    size_t off = 0;
    auto alloc = [&](size_t bytes) {
        char* p = ws + off;
        off = (off + bytes + 255) & ~(size_t)255;
        return p;
    };
    int*   FLAG = (int*)alloc(256);
    float* SACT = (float*)alloc(3 * 1536 * 4);
    float* E6   = (float*)alloc((size_t)3 * SIX * 4);
    float* EC   = (float*)alloc((size_t)3 * SIX * 4);
    bf16* NH  = (bf16*)alloc((size_t)TOTAL * DIM * 2);
    bf16* NE  = (bf16*)alloc((size_t)ENCR * DIM * 2);
    bf16* Qb  = (bf16*)alloc((size_t)TOTAL * DIM * 2);
    bf16* Kb  = (bf16*)alloc((size_t)TOTAL * DIM * 2);
    bf16* Vb  = (bf16*)alloc((size_t)TOTAL * DIM * 2);
    bf16* EQb = (bf16*)alloc((size_t)ENCR * DIM * 2);
    bf16* EKb = (bf16*)alloc((size_t)ENCR * DIM * 2);
    bf16* EVb = (bf16*)alloc((size_t)ENCR * DIM * 2);
    bf16* VJT = (bf16*)alloc((size_t)24 * 64 * (640 + 1152 + 1664) * 2);
    bf16* FF1  = (bf16*)alloc((size_t)TOTAL * INNER * 2);
    bf16* FFC1 = (bf16*)alloc((size_t)ENCR * INNER * 2);
    // transposed weights
    const size_t SQ = (size_t)DIM * DIM;          // 1536*1536
    const size_t RC = (size_t)DIM * INNER;        // 1536*6144
    bf16* WQKVT  = (bf16*)alloc(3 * SQ * 2);      // wqT|wkT|wvT  rows 0..4607
    bf16* WAQKVT = (bf16*)alloc(3 * SQ * 2);
    bf16* WOT    = (bf16*)alloc(SQ * 2);
    bf16* WAOT   = (bf16*)alloc(SQ * 2);
    bf16* FFW1T  = (bf16*)alloc(RC * 2);          // [6144][1536]
    bf16* FFW2T  = (bf16*)alloc(RC * 2);          // [1536][6144]
    bf16* FCW1T  = (bf16*)alloc(RC * 2);
    bf16* FCW2T  = (bf16*)alloc(RC * 2);
    bool useT = (off <= ws_size);

    // 0. dtype probe
    probe_kernel<<<1, 256, 0, stream>>>((const unsigned short*)ada_w, FLAG);

    // 0b. weight transposes (3 merged launches)
    if (useT) {
        wt8_kernel<<<dim3(24, 24, 8), 256, 0, stream>>>(
            wq, wk, wv, waq, wak, wav, wo, wao,
            WQKVT, WQKVT + SQ, WQKVT + 2 * SQ,
            WAQKVT, WAQKVT + SQ, WAQKVT + 2 * SQ,
            WOT, WAOT, FLAG);
        wt2_kernel<<<dim3(96, 24, 2), 256, 0, stream>>>(ffw1, fcw1, FFW1T, FCW1T, DIM, INNER, FLAG);
        wt2_kernel<<<dim3(24, 96, 2), 256, 0, stream>>>(ffw2, fcw2, FFW2T, FCW2T, INNER, DIM, FLAG);
    }

    // 1. AdaLN tables (one merged launch)
    silu_kernel<<<18, 256, 0, stream>>>(temb, SACT, FLAG);
    ada_kernel<<<288, 256, 0, stream>>>(SACT, ada_w, ada_b, E6, ada_cw, ada_cb, EC, FLAG);

    // 2. LN + modulate (msa), hid+enc merged
    ln_mod_kernel<<<TOTAL + ENCR, 256, 0, stream>>>(hid, enc, E6, EC, NH, NE, FLAG);

    // 3. QKV projections (hid+enc merged)
    if (useT) {
        gemm_t_kernel<<<dim3(36, 27), 256, 0, stream>>>(
            (const short*)NH, (const short*)NE, (const short*)WQKVT, (const short*)WAQKVT,
            bq, bk, bv, baq, bak, bav,
            Qb, Kb, Vb, EQb, EKb, EVb, 24, DIM, DIM, 0, FLAG);
    } else {
        dim3 gh(12, 24), ge(12, 3);
        gemm_kernel<<<gh, 256, 0, stream>>>((const short*)NH, wq, bq, Qb, TOTAL, DIM, DIM, 0, FLAG);
        gemm_kernel<<<gh, 256, 0, stream>>>((const short*)NH, wk, bk, Kb, TOTAL, DIM, DIM, 0, FLAG);
        gemm_kernel<<<gh, 256, 0, stream>>>((const short*)NH, wv, bv, Vb, TOTAL, DIM, DIM, 0, FLAG);
        gemm_kernel<<<ge, 256, 0, stream>>>((const short*)NE, waq, baq, EQb, ENCR, DIM, DIM, 0, FLAG);
        gemm_kernel<<<ge, 256, 0, stream>>>((const short*)NE, wak, bak, EKb, ENCR, DIM, DIM, 0, FLAG);
        gemm_kernel<<<ge, 256, 0, stream>>>((const short*)NE, wav, bav, EVb, ENCR, DIM, DIM, 0, FLAG);
    }

    // 4. fused per-head RMSNorm + RoPE on q/k (all four tensors, one launch)
    rmsrope_kernel<<<20736, 256, 0, stream>>>(Qb, Kb, EQb, EKb,
                                              nq_w, nk_w, naq_w, nak_w,
                                              rope0, rope1, rope2, FLAG);

    // 4b. V joint-transpose for PV B-fragments
    vjt_kernel<<<1296, 256, 0, stream>>>(Vb, EVb, VJT);

    // 5. MFMA flash attention (writes ATT_H->NH, ATT_E->NE)
    attn_mfma_kernel<<<1296, 256, 0, stream>>>(Qb, Kb, EQb, EKb, VJT, encv, NH, NE);

    // 6. output projections (hid+enc merged; PROJ_H->Qb, PROJ_E->EQb)
    if (useT) {
        gemm_t_kernel<<<dim3(12, 27), 256, 0, stream>>>(
            (const short*)NH, (const short*)NE, (const short*)WOT, (const short*)WAOT,
            bo, bo, bo, bao, bao, bao,
            Qb, Qb, Qb, EQb, EQb, EQb, 24, DIM, DIM, 0, FLAG);
    } else {
        dim3 gh(12, 24), ge(12, 3);
        gemm_kernel<<<gh, 256, 0, stream>>>((const short*)NH, wo, bo, Qb, TOTAL, DIM, DIM, 0, FLAG);
        gemm_kernel<<<ge, 256, 0, stream>>>((const short*)NE, wao, bao, EQb, ENCR, DIM, DIM, 0, FLAG);
    }

    // 7+8. fused gated residual #1 + LN + modulate (mlp), hid+enc merged
    //      hidden: res->Kb, ln_mod->Vb ; enc: res->EKb, ln_mod->EVb
    resid_ln_kernel<<<TOTAL + ENCR, 256, 0, stream>>>(hid, Qb, E6, Kb, Vb,
                                                      enc, EQb, EC, EKb, EVb, FLAG);

    // 9. FFN (hid+enc merged per stage)
    if (useT) {
        gemm_t_kernel<<<dim3(48, 27), 256, 0, stream>>>(
            (const short*)Vb, (const short*)EVb, (const short*)FFW1T, (const short*)FCW1T,
            ffb1, ffb1, ffb1, fcb1, fcb1, fcb1,
            FF1, FF1, FF1, FFC1, FFC1, FFC1, 24, INNER, DIM, 1, FLAG);
        gemm_t_kernel<<<dim3(12, 27), 256, 0, stream>>>(
            (const short*)FF1, (const short*)FFC1, (const short*)FFW2T, (const short*)FCW2T,
            ffb2, ffb2, ffb2, fcb2, fcb2, fcb2,
            NH, NH, NH, NE, NE, NE, 24, DIM, INNER, 0, FLAG);
    } else {
        dim3 gh(12, 24), ge(12, 3), gf1(48, 24), gf1e(48, 3);
        gemm_kernel<<<gf1, 256, 0, stream>>>((const short*)Vb, ffw1, ffb1, FF1, TOTAL, INNER, DIM, 1, FLAG);
        gemm_kernel<<<gf1e, 256, 0, stream>>>((const short*)EVb, fcw1, fcb1, FFC1, ENCR, INNER, DIM, 1, FLAG);
        gemm_kernel<<<gh, 256, 0, stream>>>((const short*)FF1, ffw2, ffb2, NH, TOTAL, DIM, INNER, 0, FLAG);
        gemm_kernel<<<ge, 256, 0, stream>>>((const short*)FFC1, fcw2, fcb2, NE, ENCR, DIM, INNER, 0, FLAG);
    }

    // 10. gated residual #2 -> packed output [e | h], one launch
    resid_out_kernel<<<20736, 256, 0, stream>>>(Kb, NH, E6, EKb, NE, EC, d_out, FLAG);
}

// Round 5
// 1025.757 us; speedup vs baseline: 1.4961x; 1.1069x over previous
//
#include <hip/hip_runtime.h>
#include <hip/hip_bf16.h>

typedef __hip_bfloat16 bf16;
typedef short s16x8 __attribute__((ext_vector_type(8)));
typedef float f32x4 __attribute__((ext_vector_type(4)));

#define DIM   1536
#define HEADS 24
#define HD    64
#define TOTAL 3072
#define ENCR  384
#define INNER 6144
#define SIX   9216

// ---- dtype-agnostic loads: flag==1 -> inputs are float32, flag==0 -> bf16
__device__ __forceinline__ float ldf(const void* p, size_t i, int f) {
    return f ? ((const float*)p)[i]
             : __bfloat162float(((const bf16*)p)[i]);
}
__device__ __forceinline__ short f2s(float v) {
    bf16 b = __float2bfloat16(v);
    short s; __builtin_memcpy(&s, &b, 2); return s;
}
__device__ __forceinline__ s16x8 ldb8(const void* B, size_t i, int f) {
    s16x8 r;
    if (f) {
        const float4* p = (const float4*)((const float*)B + i);
        float4 x = p[0], y = p[1];
        r[0]=f2s(x.x); r[1]=f2s(x.y); r[2]=f2s(x.z); r[3]=f2s(x.w);
        r[4]=f2s(y.x); r[5]=f2s(y.y); r[6]=f2s(y.z); r[7]=f2s(y.w);
    } else {
        r = *(const s16x8*)((const short*)B + i);
    }
    return r;
}
// async global->LDS, 16B per lane; lds base must be wave-uniform
__device__ __forceinline__ void gld16(const void* g, void* l) {
    __builtin_amdgcn_global_load_lds(
        (const __attribute__((address_space(1))) unsigned int*)g,
        (__attribute__((address_space(3))) unsigned int*)l, 16, 0, 0);
}

// ---------------- probe: detect input dtype (bf16 vs f32-as-shorts)
__global__ __launch_bounds__(256) void probe_kernel(const unsigned short* __restrict__ w,
                                                    int* __restrict__ flag) {
    __shared__ int cnt;
    if (threadIdx.x == 0) cnt = 0;
    __syncthreads();
    int local = 0;
    for (int i = threadIdx.x; i < 65536; i += 256) {
        unsigned short u = w[i];
        if (((u >> 7) & 0xFF) == 0xFF) local++;
    }
    atomicAdd(&cnt, local);
    __syncthreads();
    if (threadIdx.x == 0) flag[0] = (cnt > 0) ? 1 : 0;
}

// -------------------------- weight transpose body: W[K][N] -> WT[N][K] (bf16)
__device__ __forceinline__ void wt_body(const void* W, bf16* WT, int K, int N,
                                        int n0, int k0, int f) {
    __shared__ short T[64][72];
    int tid = threadIdx.x;
    int r = tid >> 2, c0 = (tid & 3) * 16;
    // vectorized loads (16B for bf16, 2x16B for f32) instead of 16 scalar loads
    s16x8 v0 = ldb8(W, (size_t)(k0 + r) * N + n0 + c0, f);
    s16x8 v1 = ldb8(W, (size_t)(k0 + r) * N + n0 + c0 + 8, f);
    *(s16x8*)&T[r][c0] = v0;
    *(s16x8*)&T[r][c0 + 8] = v1;
    __syncthreads();
    int n = tid >> 2, kc = (tid & 3) * 16;
    s16x8 o0, o1;
#pragma unroll
    for (int i = 0; i < 8; ++i) o0[i] = T[kc + i][n];
#pragma unroll
    for (int i = 0; i < 8; ++i) o1[i] = T[kc + 8 + i][n];
    short* orow = (short*)WT + (size_t)(n0 + n) * K + k0 + kc;
    *(s16x8*)orow = o0;
    *(s16x8*)(orow + 8) = o1;
}

// ---- prep mega-kernel: all 12 weight transposes + silu+ada tables, one launch
// bid [0,4608): 8 square DIMxDIM transposes (24x24 tiles each)
// bid [4608,9216): ffw1/fcw1 (K=DIM,N=INNER), 96x24 tiles each
// bid [9216,13824): ffw2/fcw2 (K=INNER,N=DIM), 24x96 tiles each
// bid [13824,14112): ada tables (silu(temb) @ W + b), silu computed in LDS
__global__ __launch_bounds__(256) void prep_kernel(
        const void* wq, const void* wk, const void* wv,
        const void* waq, const void* wak, const void* wav,
        const void* wo, const void* wao,
        bf16* dq0, bf16* dq1, bf16* dq2, bf16* dq3,
        bf16* dq4, bf16* dq5, bf16* dq6, bf16* dq7,
        const void* ffw1, const void* fcw1, bf16* FFW1T, bf16* FCW1T,
        const void* ffw2, const void* fcw2, bf16* FFW2T, bf16* FCW2T,
        const void* temb,
        const void* adaW1, const void* adaB1, float* adaO1,
        const void* adaW2, const void* adaB2, float* adaO2,
        int do_wt, const int* __restrict__ flag) {
    int f = flag[0];
    int bid = blockIdx.x;
    if (bid < 13824) {
        if (!do_wt) return;
        if (bid < 4608) {
            int m = bid / 576, w = bid % 576;
            const void* W; bf16* WT;
            switch (m) {
                case 0: W = wq;  WT = dq0; break;  case 1: W = wk;  WT = dq1; break;
                case 2: W = wv;  WT = dq2; break;  case 3: W = waq; WT = dq3; break;
                case 4: W = wak; WT = dq4; break;  case 5: W = wav; WT = dq5; break;
                case 6: W = wo;  WT = dq6; break;  default: W = wao; WT = dq7; break;
            }
            wt_body(W, WT, DIM, DIM, (w % 24) * 64, (w / 24) * 64, f);
        } else if (bid < 9216) {
            int r2 = bid - 4608;
            int m = r2 / 2304, w = r2 % 2304;
            wt_body(m ? fcw1 : ffw1, m ? FCW1T : FFW1T, DIM, INNER,
                    (w % 96) * 64, (w / 96) * 64, f);
        } else {
            int r2 = bid - 9216;
            int m = r2 / 2304, w = r2 % 2304;
            wt_body(m ? fcw2 : ffw2, m ? FCW2T : FFW2T, INNER, DIM,
                    (w % 24) * 64, (w / 24) * 64, f);
        }
        return;
    }
    // ---- ada part
    __shared__ float sact[4608];
    __shared__ float red[3][4][64];
    int tid = threadIdx.x;
    for (int i = tid; i < 4608; i += 256) {
        float x = ldf(temb, i, f);
        sact[i] = x / (1.f + __expf(-x));
    }
    __syncthreads();
    int bx = bid - 13824;
    const void* W; const void* bias; float* out;
    if (bx < 144) { W = adaW1; bias = adaB1; out = adaO1; }
    else          { W = adaW2; bias = adaB2; out = adaO2; bx -= 144; }
    int c   = tid & 63;
    int col = bx * 64 + c;
    int kq  = tid >> 6;
    float a0 = 0.f, a1 = 0.f, a2 = 0.f;
    for (int k = kq * 384; k < kq * 384 + 384; ++k) {
        float wv = ldf(W, (size_t)k * SIX + col, f);
        a0 += sact[k] * wv;
        a1 += sact[1536 + k] * wv;
        a2 += sact[3072 + k] * wv;
    }
    red[0][kq][c] = a0; red[1][kq][c] = a1; red[2][kq][c] = a2;
    __syncthreads();
    if (kq < 3) {
        float s = red[kq][0][c] + red[kq][1][c] + red[kq][2][c] + red[kq][3][c]
                + ldf(bias, col, f);
        out[(size_t)kq * SIX + col] = s;
    }
}

// ------------------------- LayerNorm + AdaLN modulate (hid + enc in one grid)
__global__ __launch_bounds__(256) void ln_mod_kernel(const void* __restrict__ xh,
                                                     const void* __restrict__ xe,
                                                     const float* __restrict__ adaH,
                                                     const float* __restrict__ adaE,
                                                     bf16* __restrict__ outh,
                                                     bf16* __restrict__ oute,
                                                     const int* __restrict__ flag) {
    int f = flag[0];
    __shared__ float r1[256], r2[256];
    int t = blockIdx.x, tid = threadIdx.x;
    const void* x; bf16* out; const float* ada; int stage;
    if (t < TOTAL) { x = xh; out = outh; ada = adaH; stage = t < 512 ? 0 : (t < 1536 ? 1 : 2); }
    else           { t -= TOTAL; x = xe; out = oute; ada = adaE; stage = t >> 7; }
    float v[6]; float s = 0.f, s2 = 0.f;
#pragma unroll
    for (int i = 0; i < 6; ++i) {
        float a = ldf(x, (size_t)t * DIM + tid + i * 256, f);
        v[i] = a; s += a; s2 += a * a;
    }
    r1[tid] = s; r2[tid] = s2;
    __syncthreads();
    for (int st = 128; st; st >>= 1) {
        if (tid < st) { r1[tid] += r1[tid + st]; r2[tid] += r2[tid + st]; }
        __syncthreads();
    }
    float mean = r1[0] * (1.f / 1536.f);
    float var  = fmaxf(r2[0] * (1.f / 1536.f) - mean * mean, 0.f);
    float inv  = rsqrtf(var + 1e-6f);
    const float* ab = ada + (size_t)stage * SIX;
#pragma unroll
    for (int i = 0; i < 6; ++i) {
        int c = tid + i * 256;
        float sc = ab[1 * DIM + c];
        float sh = ab[0 * DIM + c];
        out[(size_t)t * DIM + c] = __float2bfloat16((v[i] - mean) * inv * (1.f + sc) + sh);
    }
}

// -- fused: res = base + gate*delta (store), then LN(res)+modulate -> out (both sides)
__global__ __launch_bounds__(256) void resid_ln_kernel(const void* __restrict__ bh,
                                                       const bf16* __restrict__ dh,
                                                       const float* __restrict__ adaH,
                                                       bf16* __restrict__ resh,
                                                       bf16* __restrict__ outh,
                                                       const void* __restrict__ be,
                                                       const bf16* __restrict__ de,
                                                       const float* __restrict__ adaE,
                                                       bf16* __restrict__ rese,
                                                       bf16* __restrict__ oute,
                                                       const int* __restrict__ flag) {
    int f = flag[0];
    __shared__ float r1[256], r2[256];
    int t = blockIdx.x, tid = threadIdx.x;
    const void* base; const bf16* delta; const float* ada; bf16* res; bf16* out; int stage;
    if (t < TOTAL) { base = bh; delta = dh; ada = adaH; res = resh; out = outh;
                     stage = t < 512 ? 0 : (t < 1536 ? 1 : 2); }
    else           { t -= TOTAL; base = be; delta = de; ada = adaE; res = rese; out = oute;
                     stage = t >> 7; }
    const float* ab = ada + (size_t)stage * SIX;
    float v[6]; float s = 0.f, s2 = 0.f;
#pragma unroll
    for (int i = 0; i < 6; ++i) {
        int c = tid + i * 256;
        size_t gi = (size_t)t * DIM + c;
        float g = ab[2 * DIM + c];
        float a = ldf(base, gi, f) + g * __bfloat162float(delta[gi]);
        res[gi] = __float2bfloat16(a);
        v[i] = a; s += a; s2 += a * a;
    }
    r1[tid] = s; r2[tid] = s2;
    __syncthreads();
    for (int st = 128; st; st >>= 1) {
        if (tid < st) { r1[tid] += r1[tid + st]; r2[tid] += r2[tid + st]; }
        __syncthreads();
    }
    float mean = r1[0] * (1.f / 1536.f);
    float var  = fmaxf(r2[0] * (1.f / 1536.f) - mean * mean, 0.f);
    float inv  = rsqrtf(var + 1e-6f);
#pragma unroll
    for (int i = 0; i < 6; ++i) {
        int c = tid + i * 256;
        float sc = ab[4 * DIM + c];
        float sh = ab[3 * DIM + c];
        out[(size_t)t * DIM + c] = __float2bfloat16((v[i] - mean) * inv * (1.f + sc) + sh);
    }
}

// ------------------------- transposed-B MFMA GEMM, 4-buffer single-barrier pipeline
// C[M, Nout(xn)] = act(A[M,K] @ Bt[N,K]^T + bias).  128x128 tile, BK=32 per
// buffer, 4 distinct LDS buffer pairs (64 KB).  Per K-step t:
//   stage(t+2) into buf[(t+2)&3] -> s_waitcnt vmcnt(8) [stage t complete,
//   t+1/t+2 in flight] -> s_barrier -> sched_barrier -> ds_read+MFMA buf[t&3].
// The 4-deep rotation makes the trailing lgkmcnt(0)+barrier unnecessary:
// buf[(t+2)&3] was last READ at step t-2, and barrier(t-1) already orders all
// waves' t-2 ds_read completion (forced by MFMA operand waits, which precede
// each wave's step-(t-1) stage issue in program order) against any wave's
// step-t stage write.  One barrier per step instead of two.
// Handles hidden-side (by<yh) and enc-side (by>=yh) problems in one grid, and
// applies the m204 bijective XCD chunk swizzle for L2 panel locality.
__global__ __launch_bounds__(256) void gemm_t_kernel(const short* __restrict__ Ah,
                                                     const short* __restrict__ Ae,
                                                     const short* __restrict__ Bth,
                                                     const short* __restrict__ Bte,
                                                     const void* Bh0, const void* Bh1, const void* Bh2,
                                                     const void* Be0, const void* Be1, const void* Be2,
                                                     bf16* Oh0, bf16* Oh1, bf16* Oh2,
                                                     bf16* Oe0, bf16* Oe1, bf16* Oe2,
                                                     int yh, int Nout, int K, int act,
                                                     const int* __restrict__ flag) {
    int f = flag[0];
    __shared__ __align__(16) short As0[128 * 32];
    __shared__ __align__(16) short As1[128 * 32];
    __shared__ __align__(16) short As2[128 * 32];
    __shared__ __align__(16) short As3[128 * 32];
    __shared__ __align__(16) short Bs0[128 * 32];
    __shared__ __align__(16) short Bs1[128 * 32];
    __shared__ __align__(16) short Bs2[128 * 32];
    __shared__ __align__(16) short Bs3[128 * 32];
    int tid = threadIdx.x;
    int lane = tid & 63, wid = tid >> 6;
    int wy = wid >> 1, wx = wid & 1;
    int lane15 = lane & 15, quad = lane >> 4;

    // bijective XCD chunk swizzle (m204): contiguous logical tiles per XCD
    int gx = gridDim.x;
    int nwg = gx * gridDim.y;
    int orig = blockIdx.y * gx + blockIdx.x;
    int q = nwg >> 3, r = nwg & 7;
    int x8 = orig & 7, o8 = orig >> 3;
    int wg = (x8 < r) ? x8 * (q + 1) + o8 : r * (q + 1) + (x8 - r) * q + o8;
    int bx = wg % gx, by = wg / gx;

    const short* A; const short* Bt; int m0;
    const void *b0, *b1, *b2; bf16 *o0, *o1, *o2;
    if (by < yh) { A = Ah; Bt = Bth; m0 = by * 128;
                   b0 = Bh0; b1 = Bh1; b2 = Bh2; o0 = Oh0; o1 = Oh1; o2 = Oh2; }
    else         { A = Ae; Bt = Bte; m0 = (by - yh) * 128;
                   b0 = Be0; b1 = Be1; b2 = Be2; o0 = Oe0; o1 = Oe1; o2 = Oe2; }
    int n0 = bx * 128;
    int lr = lane >> 2, lc = lane & 3;

    f32x4 acc[4][4] = {};

    auto stage = [&](short* Ad, short* Bd, int k0) {
#pragma unroll
        for (int c = 0; c < 2; ++c) {
            int rb = wid * 32 + c * 16;
            int rr = rb + lr;
            int gc = (lc - (rr >> 1)) & 3;
            gld16(A  + (size_t)(m0 + rr) * K + k0 + gc * 8, Ad + rb * 32);
            gld16(Bt + (size_t)(n0 + rr) * K + k0 + gc * 8, Bd + rb * 32);
        }
    };
    auto compute = [&](const short* Ash, const short* Bsh) {
        s16x8 af[4], bfr[4];
#pragma unroll
        for (int i = 0; i < 4; ++i) {
            int ra = wy * 64 + i * 16 + lane15;
            af[i] = *(const s16x8*)&Ash[ra * 32 + ((quad + (ra >> 1)) & 3) * 8];
            int rb2 = wx * 64 + i * 16 + lane15;
            bfr[i] = *(const s16x8*)&Bsh[rb2 * 32 + ((quad + (rb2 >> 1)) & 3) * 8];
        }
#pragma unroll
        for (int im = 0; im < 4; ++im)
#pragma unroll
            for (int in = 0; in < 4; ++in)
                acc[im][in] = __builtin_amdgcn_mfma_f32_16x16x32_bf16(
                    af[im], bfr[in], acc[im][in], 0, 0, 0);
    };
    int nt = K >> 5;   // 48 or 192; always divisible by 4
    auto step = [&](const short* Ac, const short* Bc, short* An, short* Bn, int tt) {
        int nx = tt + 2;
        if (nx < nt) {
            stage(An, Bn, nx << 5);
            asm volatile("s_waitcnt vmcnt(8)" ::: "memory");
        } else if (tt + 1 < nt) {
            asm volatile("s_waitcnt vmcnt(4)" ::: "memory");
        } else {
            asm volatile("s_waitcnt vmcnt(0)" ::: "memory");
        }
        __builtin_amdgcn_s_barrier();
        __builtin_amdgcn_sched_barrier(0);
        compute(Ac, Bc);
    };

    stage(As0, Bs0, 0);
    stage(As1, Bs1, 32);
    for (int t = 0; t < nt; t += 4) {
        step(As0, Bs0, As2, Bs2, t);
        step(As1, Bs1, As3, Bs3, t + 1);
        step(As2, Bs2, As0, Bs0, t + 2);
        step(As3, Bs3, As1, Bs1, t + 3);
    }

    int sel = n0 / Nout;
    int nb = n0 - sel * Nout;
    bf16* Cout = sel == 0 ? o0 : (sel == 1 ? o1 : o2);
    const void* bs = sel == 0 ? b0 : (sel == 1 ? b1 : b2);

#pragma unroll
    for (int in = 0; in < 4; ++in) {
        int gn = nb + wx * 64 + in * 16 + lane15;
        float bsv = ldf(bs, gn, f);
#pragma unroll
        for (int im = 0; im < 4; ++im) {
#pragma unroll
            for (int rr = 0; rr < 4; ++rr) {
                int gm = m0 + wy * 64 + im * 16 + quad * 4 + rr;
                float v = acc[im][in][rr] + bsv;
                if (act == 1) {
                    float u = 0.7978845608028654f * (v + 0.044715f * v * v * v);
                    float e = __expf(2.f * u);
                    v = 0.5f * v * (1.f + (1.f - 2.f / (e + 1.f)));
                }
                Cout[(size_t)gm * Nout + gn] = __float2bfloat16(v);
            }
        }
    }
}

// ---------------------------------------------------------------- legacy GEMM
// (fallback when ws is too small for transposed weights)
#define LDK 48
__global__ __launch_bounds__(256) void gemm_kernel(const short* __restrict__ A,
                                                   const void* __restrict__ B,
                                                   const void* __restrict__ bias,
                                                   bf16* __restrict__ C,
                                                   int M, int N, int K, int act,
                                                   const int* __restrict__ flag) {
    int f = flag[0];
    __shared__ __align__(16) short As[128 * LDK];
    __shared__ __align__(16) short Bs[128 * LDK];
    int tid = threadIdx.x;
    int lane = tid & 63, wid = tid >> 6;
    int wy = wid >> 1, wx = wid & 1;
    int m16 = lane & 15, quad = lane >> 4;
    int m0 = blockIdx.y * 128, n0 = blockIdx.x * 128;
    int ar0 = tid >> 2;
    int ac  = (tid & 3) * 8;
    int br0 = tid >> 4;
    int bc  = (tid & 15) * 8;
    f32x4 acc[4][4] = {};
    for (int k0 = 0; k0 < K; k0 += 32) {
        s16x8 a0 = *(const s16x8*)(A + (size_t)(m0 + ar0) * K + k0 + ac);
        s16x8 a1 = *(const s16x8*)(A + (size_t)(m0 + ar0 + 64) * K + k0 + ac);
        s16x8 b0 = ldb8(B, (size_t)(k0 + br0) * N + n0 + bc, f);
        s16x8 b1 = ldb8(B, (size_t)(k0 + br0 + 16) * N + n0 + bc, f);
        __syncthreads();
        *(s16x8*)(&As[ar0 * LDK + ac]) = a0;
        *(s16x8*)(&As[(ar0 + 64) * LDK + ac]) = a1;
#pragma unroll
        for (int i = 0; i < 8; ++i) {
            Bs[(bc + i) * LDK + br0] = b0[i];
            Bs[(bc + i) * LDK + br0 + 16] = b1[i];
        }
        __syncthreads();
        s16x8 af[4], bfr[4];
#pragma unroll
        for (int i = 0; i < 4; ++i) {
            af[i]  = *(const s16x8*)(&As[(wy * 64 + i * 16 + m16) * LDK + quad * 8]);
            bfr[i] = *(const s16x8*)(&Bs[(wx * 64 + i * 16 + m16) * LDK + quad * 8]);
        }
#pragma unroll
        for (int im = 0; im < 4; ++im)
#pragma unroll
            for (int in = 0; in < 4; ++in)
                acc[im][in] = __builtin_amdgcn_mfma_f32_16x16x32_bf16(
                    af[im], bfr[in], acc[im][in], 0, 0, 0);
    }
#pragma unroll
    for (int in = 0; in < 4; ++in) {
        int gn = n0 + wx * 64 + in * 16 + m16;
        float bsv = ldf(bias, gn, f);
#pragma unroll
        for (int im = 0; im < 4; ++im) {
#pragma unroll
            for (int r = 0; r < 4; ++r) {
                int gm = m0 + wy * 64 + im * 16 + quad * 4 + r;
                float v = acc[im][in][r] + bsv;
                if (act == 1) {
                    float u = 0.7978845608028654f * (v + 0.044715f * v * v * v);
                    float e = __expf(2.f * u);
                    v = 0.5f * v * (1.f + (1.f - 2.f / (e + 1.f)));
                }
                C[(size_t)gm * N + gn] = __float2bfloat16(v);
            }
        }
    }
}

// --------- fused per-(token,head) RMSNorm + RoPE (Q,K,EQ,EK) AND VJt build,
// one launch.  bid < 20736: rmsrope; bid >= 20736: vjt (independent tensors).
__global__ __launch_bounds__(256) void rmsvjt_kernel(bf16* __restrict__ Qb,
                                                     bf16* __restrict__ Kb,
                                                     bf16* __restrict__ EQb,
                                                     bf16* __restrict__ EKb,
                                                     const void* __restrict__ nq,
                                                     const void* __restrict__ nk,
                                                     const void* __restrict__ naq,
                                                     const void* __restrict__ nak,
                                                     const void* __restrict__ r0,
                                                     const void* __restrict__ r1,
                                                     const void* __restrict__ r2,
                                                     const bf16* __restrict__ Vb,
                                                     const bf16* __restrict__ EVb,
                                                     bf16* __restrict__ VJt,
                                                     const int* __restrict__ flag) {
    int f = flag[0];
    int bid = blockIdx.x;
    if (bid >= 20736) {
        // ---------------- vjt part
        __shared__ short T[64][72];
        int b = bid - 20736;
        int h = b % 24, jt = b / 24;
        int s, j0, S, hbase; size_t off;
        if (jt < 10)      { s = 0; j0 = jt * 64;        S = 640;  hbase = 0;    off = 0; }
        else if (jt < 28) { s = 1; j0 = (jt - 10) * 64; S = 1152; hbase = 512;  off = (size_t)24 * 64 * 640; }
        else              { s = 2; j0 = (jt - 28) * 64; S = 1664; hbase = 1536; off = (size_t)24 * 64 * (640 + 1152); }
        int tid = threadIdx.x;
        int tr = tid >> 2, tc = (tid & 3) * 16;
        int j = j0 + tr;
        const bf16* vr = (j < 128) ? EVb + ((size_t)(s * 128 + j) * DIM + h * HD)
                                   : Vb + ((size_t)(hbase + j - 128) * DIM + h * HD);
        *(s16x8*)&T[tr][tc]     = *(const s16x8*)((const short*)vr + tc);
        *(s16x8*)&T[tr][tc + 8] = *(const s16x8*)((const short*)vr + tc + 8);
        __syncthreads();
        int d = tid >> 2, c0 = (tid & 3) * 16;
        s16x8 o0, o1;
#pragma unroll
        for (int i = 0; i < 8; ++i) o0[i] = T[c0 + i][d];
#pragma unroll
        for (int i = 0; i < 8; ++i) o1[i] = T[c0 + 8 + i][d];
        short* orow = (short*)VJt + off + (size_t)(h * HD + d) * S + j0 + c0;
        *(s16x8*)orow = o0;
        *(s16x8*)(orow + 8) = o1;
        return;
    }
    // ---------------- rmsrope part
    bf16* x; const void* w; int is_enc;
    if (bid < 9216)       { x = Qb;  w = nq;  is_enc = 0; }
    else if (bid < 18432) { x = Kb;  w = nk;  is_enc = 0; bid -= 9216; }
    else if (bid < 19584) { x = EQb; w = naq; is_enc = 1; bid -= 18432; }
    else                  { x = EKb; w = nak; is_enc = 1; bid -= 19584; }
    int grp = bid * 8 + (threadIdx.x >> 5);
    int l = threadIdx.x & 31;
    int t = grp / 24;
    size_t base = (size_t)grp * 64 + 2 * l;
    unsigned int u = *(const unsigned int*)((const short*)x + base);
    union { unsigned int ui; float fl; } a, b2;
    a.ui = (u & 0xFFFFu) << 16;
    b2.ui = u & 0xFFFF0000u;
    float x0 = a.fl, x1 = b2.fl;
    float ss = x0 * x0 + x1 * x1;
#pragma unroll
    for (int off = 1; off < 32; off <<= 1) ss += __shfl_xor(ss, off);
    float inv = rsqrtf(ss * (1.f / 64.f) + 1e-6f);
    float xw0 = x0 * inv * ldf(w, 2 * l, f);
    float xw1 = x1 * inv * ldf(w, 2 * l + 1, f);
    int stage, pos;
    if (is_enc)        { stage = t >> 7; pos = t & 127; }
    else if (t < 512)  { stage = 0; pos = 128 + t; }
    else if (t < 1536) { stage = 1; pos = 128 + t - 512; }
    else               { stage = 2; pos = 128 + t - 1536; }
    const void* rt = stage == 0 ? r0 : (stage == 1 ? r1 : r2);
    size_t ro = ((size_t)pos * 32 + l) * 4;
    float c00 = ldf(rt, ro + 0, f);
    float c01 = ldf(rt, ro + 1, f);
    float c10 = ldf(rt, ro + 2, f);
    float c11 = ldf(rt, ro + 3, f);
    unsigned int q0 = (unsigned int)(unsigned short)f2s(c00 * xw0 + c01 * xw1);
    unsigned int q1 = (unsigned int)(unsigned short)f2s(c10 * xw0 + c11 * xw1);
    *(unsigned int*)((short*)x + base) = (q1 << 16) | q0;
}

// -------------------------------------------------- MFMA tiled flash attention
__global__ __launch_bounds__(256) void attn_mfma_kernel(const bf16* __restrict__ Qb,
                                                        const bf16* __restrict__ Kb,
                                                        const bf16* __restrict__ EQ,
                                                        const bf16* __restrict__ EK,
                                                        const bf16* __restrict__ VJt,
                                                        const int* __restrict__ encv,
                                                        bf16* __restrict__ AH,
                                                        bf16* __restrict__ AE) {
    __shared__ __align__(16) short Ks[64 * 72];
    __shared__ __align__(16) short Vt[64 * 72];
    __shared__ __align__(16) short Ps[4][16 * 72];
    int tid = threadIdx.x, wid = tid >> 6, lane = tid & 63;
    int lane15 = lane & 15, quad = lane >> 4;
    int b = (int)gridDim.x - 1 - (int)blockIdx.x;
    int h = b % 24, qt = b / 24;
    int s, qt0, S, hbase; size_t voff;
    if (qt < 10)      { s = 0; qt0 = qt;      S = 640;  hbase = 0;    voff = 0; }
    else if (qt < 28) { s = 1; qt0 = qt - 10; S = 1152; hbase = 512;  voff = (size_t)24 * 64 * 640; }
    else              { s = 2; qt0 = qt - 28; S = 1664; hbase = 1536; voff = (size_t)24 * 64 * (640 + 1152); }
    const short* vbase = (const short*)VJt + voff + (size_t)h * HD * S;
    int ev = encv[s];
    int qbase = qt0 * 64 + wid * 16;

    int q = qbase + lane15;
    const short* qrow = (q < 128)
        ? (const short*)EQ + ((size_t)(s * 128 + q) * DIM + h * HD)
        : (const short*)Qb + ((size_t)(hbase + q - 128) * DIM + h * HD);
    s16x8 qa[2];
#pragma unroll
    for (int k0 = 0; k0 < 2; ++k0) {
        s16x8 x = *(const s16x8*)(qrow + k0 * 32 + quad * 8);
#pragma unroll
        for (int i = 0; i < 8; ++i) {
            union { unsigned int u; float fl; } t;
            t.u = ((unsigned int)(unsigned short)x[i]) << 16;
            t.fl *= 0.125f;
            x[i] = (short)(t.u >> 16);
        }
        qa[k0] = x;
    }

    f32x4 o[4] = {};
    float mrun[4] = {-1e30f, -1e30f, -1e30f, -1e30f};
    float lrun[4] = {};

    int nkb = S >> 6;
    for (int kb = 0; kb < nkb; ++kb) {
        __syncthreads();
        {
            int kr = tid >> 2, kc = (tid & 3) * 16;
            int kg = kb * 64 + kr;
            const short* krow = (kg < 128)
                ? (const short*)EK + ((size_t)(s * 128 + kg) * DIM + h * HD)
                : (const short*)Kb + ((size_t)(hbase + kg - 128) * DIM + h * HD);
            *(s16x8*)&Ks[kr * 72 + kc]     = *(const s16x8*)(krow + kc);
            *(s16x8*)&Ks[kr * 72 + kc + 8] = *(const s16x8*)(krow + kc + 8);
        }
        {
            int vd = tid >> 2, vc = (tid & 3) * 16;
            const short* vrow = vbase + (size_t)vd * S + kb * 64 + vc;
            *(s16x8*)&Vt[vd * 72 + vc]     = *(const s16x8*)(vrow);
            *(s16x8*)&Vt[vd * 72 + vc + 8] = *(const s16x8*)(vrow + 8);
        }
        __syncthreads();

        f32x4 sacc[4];
        __builtin_amdgcn_s_setprio(1);
#pragma unroll
        for (int g = 0; g < 4; ++g) {
            s16x8 kf0 = *(const s16x8*)&Ks[(g * 16 + lane15) * 72 + quad * 8];
            s16x8 kf1 = *(const s16x8*)&Ks[(g * 16 + lane15) * 72 + 32 + quad * 8];
            f32x4 c = {};
            c = __builtin_amdgcn_mfma_f32_16x16x32_bf16(qa[0], kf0, c, 0, 0, 0);
            c = __builtin_amdgcn_mfma_f32_16x16x32_bf16(qa[1], kf1, c, 0, 0, 0);
            sacc[g] = c;
        }
        __builtin_amdgcn_s_setprio(0);
        if (kb == 1) {             // keys 64..127 are the only maskable ones (ev>=64)
#pragma unroll
            for (int g = 0; g < 4; ++g) {
                int keyg = 64 + g * 16 + lane15;
                if (keyg >= ev) {
#pragma unroll
                    for (int r = 0; r < 4; ++r) sacc[g][r] = -1e30f;
                }
            }
        }
        float mt[4], al[4], ps[4];
#pragma unroll
        for (int r = 0; r < 4; ++r)
            mt[r] = fmaxf(fmaxf(sacc[0][r], sacc[1][r]), fmaxf(sacc[2][r], sacc[3][r]));
#pragma unroll
        for (int off = 1; off < 16; off <<= 1)
#pragma unroll
            for (int r = 0; r < 4; ++r) mt[r] = fmaxf(mt[r], __shfl_xor(mt[r], off));
#pragma unroll
        for (int r = 0; r < 4; ++r) {
            float mn = fmaxf(mrun[r], mt[r]);
            al[r] = __expf(mrun[r] - mn);
            mrun[r] = mn;
        }
#pragma unroll
        for (int g = 0; g < 4; ++g)
#pragma unroll
            for (int r = 0; r < 4; ++r)
                sacc[g][r] = __expf(sacc[g][r] - mrun[r]);
#pragma unroll
        for (int r = 0; r < 4; ++r)
            ps[r] = (sacc[0][r] + sacc[1][r]) + (sacc[2][r] + sacc[3][r]);
#pragma unroll
        for (int off = 1; off < 16; off <<= 1)
#pragma unroll
            for (int r = 0; r < 4; ++r) ps[r] += __shfl_xor(ps[r], off);
#pragma unroll
        for (int r = 0; r < 4; ++r) lrun[r] = lrun[r] * al[r] + ps[r];
#pragma unroll
        for (int dc = 0; dc < 4; ++dc)
#pragma unroll
            for (int r = 0; r < 4; ++r) o[dc][r] *= al[r];
#pragma unroll
        for (int g = 0; g < 4; ++g)
#pragma unroll
            for (int r = 0; r < 4; ++r)
                Ps[wid][(quad * 4 + r) * 72 + g * 16 + lane15] = f2s(sacc[g][r]);
        s16x8 pa0 = *(const s16x8*)&Ps[wid][lane15 * 72 + quad * 8];
        s16x8 pa1 = *(const s16x8*)&Ps[wid][lane15 * 72 + 32 + quad * 8];
        __builtin_amdgcn_s_setprio(1);
#pragma unroll
        for (int dc = 0; dc < 4; ++dc) {
            s16x8 vf0 = *(const s16x8*)&Vt[(dc * 16 + lane15) * 72 + quad * 8];
            s16x8 vf1 = *(const s16x8*)&Vt[(dc * 16 + lane15) * 72 + 32 + quad * 8];
            o[dc] = __builtin_amdgcn_mfma_f32_16x16x32_bf16(pa0, vf0, o[dc], 0, 0, 0);
            o[dc] = __builtin_amdgcn_mfma_f32_16x16x32_bf16(pa1, vf1, o[dc], 0, 0, 0);
        }
        __builtin_amdgcn_s_setprio(0);
    }

    float invl[4];
#pragma unroll
    for (int r = 0; r < 4; ++r) invl[r] = 1.f / fmaxf(lrun[r], 1e-37f);
#pragma unroll
    for (int r = 0; r < 4; ++r) {
        int qr = qbase + quad * 4 + r;
        bf16* orow = (qr < 128)
            ? AE + ((size_t)(s * 128 + qr) * DIM + h * HD)
            : AH + ((size_t)(hbase + qr - 128) * DIM + h * HD);
#pragma unroll
        for (int dc = 0; dc < 4; ++dc)
            orow[dc * 16 + lane15] = __float2bfloat16(o[dc][r] * invl[r]);
    }
}

// --------------------- final gated residuals -> packed output [e | h]
__global__ __launch_bounds__(256) void resid_out_kernel(const bf16* __restrict__ bh,
                                                        const bf16* __restrict__ dh,
                                                        const float* __restrict__ adaH,
                                                        const bf16* __restrict__ be,
                                                        const bf16* __restrict__ de,
                                                        const float* __restrict__ adaE,
                                                        void* __restrict__ out,
                                                        const int* __restrict__ flag) {
    int ofl = flag[0];
    int bid = blockIdx.x, tid = threadIdx.x;
    float v; size_t oidx;
    if (bid < 2304) {
        int gid = bid * 256 + tid;
        int t = gid / DIM, c = gid - t * DIM;
        int st = t >> 7;
        v = __bfloat162float(be[gid]) + adaE[(size_t)st * SIX + 5 * DIM + c] * __bfloat162float(de[gid]);
        oidx = gid;
    } else {
        int gid = (bid - 2304) * 256 + tid;
        int t = gid / DIM, c = gid - t * DIM;
        int st = t < 512 ? 0 : (t < 1536 ? 1 : 2);
        v = __bfloat162float(bh[gid]) + adaH[(size_t)st * SIX + 5 * DIM + c] * __bfloat162float(dh[gid]);
        oidx = (size_t)ENCR * DIM + gid;
    }
    if (ofl) ((float*)out)[oidx] = v;
    else     ((bf16*)out)[oidx] = __float2bfloat16(v);
}

extern "C" void kernel_launch(void* const* d_in, const int* in_sizes, int n_in,
                              void* d_out, int out_size, void* d_ws, size_t ws_size,
                              hipStream_t stream) {
    (void)in_sizes; (void)n_in; (void)out_size;
    const void* hid   = d_in[0];
    const void* enc   = d_in[1];
    const void* temb  = d_in[2];
    const int*  encv  = (const int*)d_in[3];
    const void* rope0 = d_in[4];
    const void* rope1 = d_in[5];
    const void* rope2 = d_in[6];
    const void* ada_w = d_in[7];  const void* ada_b = d_in[8];
    const void* ada_cw = d_in[9]; const void* ada_cb = d_in[10];
    const void* wq = d_in[11]; const void* bq = d_in[12];
    const void* wk = d_in[13]; const void* bk = d_in[14];
    const void* wv = d_in[15]; const void* bv = d_in[16];
    const void* waq = d_in[17]; const void* baq = d_in[18];
    const void* wak = d_in[19]; const void* bak = d_in[20];
    const void* wav = d_in[21]; const void* bav = d_in[22];
    const void* nq_w = d_in[23];
    const void* nk_w = d_in[24];
    const void* naq_w = d_in[25];
    const void* nak_w = d_in[26];
    const void* wo = d_in[27]; const void* bo = d_in[28];
    const void* wao = d_in[29]; const void* bao = d_in[30];
    const void* ffw1 = d_in[31]; const void* ffb1 = d_in[32];
    const void* ffw2 = d_in[33]; const void* ffb2 = d_in[34];
    const void* fcw1 = d_in[35]; const void* fcb1 = d_in[36];
    const void* fcw2 = d_in[37]; const void* fcb2 = d_in[38];

    char* ws = (char*)d_ws;
    size_t off = 0;
    auto alloc = [&](size_t bytes) {
        char* p = ws + off;
        off = (off + bytes + 255) & ~(size_t)255;
        return p;
    };
    int*   FLAG = (int*)alloc(256);
    float* E6   = (float*)alloc((size_t)3 * SIX * 4);
    float* EC   = (float*)alloc((size_t)3 * SIX * 4);
    bf16* NH  = (bf16*)alloc((size_t)TOTAL * DIM * 2);
    bf16* NE  = (bf16*)alloc((size_t)ENCR * DIM * 2);
    bf16* Qb  = (bf16*)alloc((size_t)TOTAL * DIM * 2);
    bf16* Kb  = (bf16*)alloc((size_t)TOTAL * DIM * 2);
    bf16* Vb  = (bf16*)alloc((size_t)TOTAL * DIM * 2);
    bf16* EQb = (bf16*)alloc((size_t)ENCR * DIM * 2);
    bf16* EKb = (bf16*)alloc((size_t)ENCR * DIM * 2);
    bf16* EVb = (bf16*)alloc((size_t)ENCR * DIM * 2);
    bf16* VJT = (bf16*)alloc((size_t)24 * 64 * (640 + 1152 + 1664) * 2);
    bf16* FF1  = (bf16*)alloc((size_t)TOTAL * INNER * 2);
    bf16* FFC1 = (bf16*)alloc((size_t)ENCR * INNER * 2);
    // transposed weights
    const size_t SQ = (size_t)DIM * DIM;          // 1536*1536
    const size_t RC = (size_t)DIM * INNER;        // 1536*6144
    bf16* WQKVT  = (bf16*)alloc(3 * SQ * 2);      // wqT|wkT|wvT  rows 0..4607
    bf16* WAQKVT = (bf16*)alloc(3 * SQ * 2);
    bf16* WOT    = (bf16*)alloc(SQ * 2);
    bf16* WAOT   = (bf16*)alloc(SQ * 2);
    bf16* FFW1T  = (bf16*)alloc(RC * 2);          // [6144][1536]
    bf16* FFW2T  = (bf16*)alloc(RC * 2);          // [1536][6144]
    bf16* FCW1T  = (bf16*)alloc(RC * 2);
    bf16* FCW2T  = (bf16*)alloc(RC * 2);
    bool useT = (off <= ws_size);

    // 1. dtype probe
    probe_kernel<<<1, 256, 0, stream>>>((const unsigned short*)ada_w, FLAG);

    // 2. prep: all weight transposes + silu+ada tables, one launch
    prep_kernel<<<14112, 256, 0, stream>>>(
        wq, wk, wv, waq, wak, wav, wo, wao,
        WQKVT, WQKVT + SQ, WQKVT + 2 * SQ,
        WAQKVT, WAQKVT + SQ, WAQKVT + 2 * SQ, WOT, WAOT,
        ffw1, fcw1, FFW1T, FCW1T,
        ffw2, fcw2, FFW2T, FCW2T,
        temb, ada_w, ada_b, E6, ada_cw, ada_cb, EC,
        useT ? 1 : 0, FLAG);

    // 3. LN + modulate (msa), hid+enc merged
    ln_mod_kernel<<<TOTAL + ENCR, 256, 0, stream>>>(hid, enc, E6, EC, NH, NE, FLAG);

    // 4. QKV projections (hid+enc merged)
    if (useT) {
        gemm_t_kernel<<<dim3(36, 27), 256, 0, stream>>>(
            (const short*)NH, (const short*)NE, (const short*)WQKVT, (const short*)WAQKVT,
            bq, bk, bv, baq, bak, bav,
            Qb, Kb, Vb, EQb, EKb, EVb, 24, DIM, DIM, 0, FLAG);
    } else {
        dim3 gh(12, 24), ge(12, 3);
        gemm_kernel<<<gh, 256, 0, stream>>>((const short*)NH, wq, bq, Qb, TOTAL, DIM, DIM, 0, FLAG);
        gemm_kernel<<<gh, 256, 0, stream>>>((const short*)NH, wk, bk, Kb, TOTAL, DIM, DIM, 0, FLAG);
        gemm_kernel<<<gh, 256, 0, stream>>>((const short*)NH, wv, bv, Vb, TOTAL, DIM, DIM, 0, FLAG);
        gemm_kernel<<<ge, 256, 0, stream>>>((const short*)NE, waq, baq, EQb, ENCR, DIM, DIM, 0, FLAG);
        gemm_kernel<<<ge, 256, 0, stream>>>((const short*)NE, wak, bak, EKb, ENCR, DIM, DIM, 0, FLAG);
        gemm_kernel<<<ge, 256, 0, stream>>>((const short*)NE, wav, bav, EVb, ENCR, DIM, DIM, 0, FLAG);
    }

    // 5. fused RMSNorm+RoPE (Q,K,EQ,EK) + V joint-transpose, one launch
    rmsvjt_kernel<<<20736 + 1296, 256, 0, stream>>>(Qb, Kb, EQb, EKb,
                                                    nq_w, nk_w, naq_w, nak_w,
                                                    rope0, rope1, rope2,
                                                    Vb, EVb, VJT, FLAG);

    // 6. MFMA flash attention (writes ATT_H->NH, ATT_E->NE)
    attn_mfma_kernel<<<1296, 256, 0, stream>>>(Qb, Kb, EQb, EKb, VJT, encv, NH, NE);

    // 7. output projections (hid+enc merged; PROJ_H->Qb, PROJ_E->EQb)
    if (useT) {
        gemm_t_kernel<<<dim3(12, 27), 256, 0, stream>>>(
            (const short*)NH, (const short*)NE, (const short*)WOT, (const short*)WAOT,
            bo, bo, bo, bao, bao, bao,
            Qb, Qb, Qb, EQb, EQb, EQb, 24, DIM, DIM, 0, FLAG);
    } else {
        dim3 gh(12, 24), ge(12, 3);
        gemm_kernel<<<gh, 256, 0, stream>>>((const short*)NH, wo, bo, Qb, TOTAL, DIM, DIM, 0, FLAG);
        gemm_kernel<<<ge, 256, 0, stream>>>((const short*)NE, wao, bao, EQb, ENCR, DIM, DIM, 0, FLAG);
    }

    // 8. fused gated residual #1 + LN + modulate (mlp), hid+enc merged
    //    hidden: res->Kb, ln_mod->Vb ; enc: res->EKb, ln_mod->EVb
    resid_ln_kernel<<<TOTAL + ENCR, 256, 0, stream>>>(hid, Qb, E6, Kb, Vb,
                                                      enc, EQb, EC, EKb, EVb, FLAG);

    // 9. FFN (hid+enc merged per stage)
    if (useT) {
        gemm_t_kernel<<<dim3(48, 27), 256, 0, stream>>>(
            (const short*)Vb, (const short*)EVb, (const short*)FFW1T, (const short*)FCW1T,
            ffb1, ffb1, ffb1, fcb1, fcb1, fcb1,
            FF1, FF1, FF1, FFC1, FFC1, FFC1, 24, INNER, DIM, 1, FLAG);
        gemm_t_kernel<<<dim3(12, 27), 256, 0, stream>>>(
            (const short*)FF1, (const short*)FFC1, (const short*)FFW2T, (const short*)FCW2T,
            ffb2, ffb2, ffb2, fcb2, fcb2, fcb2,
            NH, NH, NH, NE, NE, NE, 24, DIM, INNER, 0, FLAG);
    } else {
        dim3 gh(12, 24), ge(12, 3), gf1(48, 24), gf1e(48, 3);
        gemm_kernel<<<gf1, 256, 0, stream>>>((const short*)Vb, ffw1, ffb1, FF1, TOTAL, INNER, DIM, 1, FLAG);
        gemm_kernel<<<gf1e, 256, 0, stream>>>((const short*)EVb, fcw1, fcb1, FFC1, ENCR, INNER, DIM, 1, FLAG);
        gemm_kernel<<<gh, 256, 0, stream>>>((const short*)FF1, ffw2, ffb2, NH, TOTAL, DIM, INNER, 0, FLAG);
        gemm_kernel<<<ge, 256, 0, stream>>>((const short*)FFC1, fcw2, fcb2, NE, ENCR, DIM, INNER, 0, FLAG);
    }

    // 10. gated residual #2 -> packed output [e | h], one launch
    resid_out_kernel<<<20736, 256, 0, stream>>>(Kb, NH, E6, EKb, NE, EC, d_out, FLAG);
}